// Round 5
// baseline (14264.886 us; speedup 1.0000x reference)
//
#include <hip/hip_runtime.h>
#include <hip/hip_cooperative_groups.h>
#include <math.h>

namespace cg = cooperative_groups;

// ImuModel v5: persistent cooperative ConvLSTM, 256 blocks x 512 threads.
// Block = two 256-thread halves in lockstep: half0 = conv1[t] tile,
// half1 = conv0[t+1] tile (common-site __syncthreads). 2 grid.sync per step.
// Fallback: if hipLaunchCooperativeKernel fails, per-step launches of the
// same device code (stepA/stepB) — 130 launches.

typedef __attribute__((ext_vector_type(8))) short     bf16x8;
typedef __attribute__((ext_vector_type(8))) unsigned short u16x8;
typedef __attribute__((ext_vector_type(4))) float     f32x4;
typedef unsigned short u16;

__device__ __forceinline__ float hsig(float x) {
    return fminf(fmaxf(0.2f * x + 0.5f, 0.0f), 1.0f);
}
__device__ __forceinline__ float bf2f(u16 u) {
    union { unsigned int i; float f; } v; v.i = ((unsigned int)u) << 16; return v.f;
}
__device__ __forceinline__ u16 f2bf(float f) {
    union { float f; unsigned int i; } v; v.f = f;
    unsigned int r = (v.i + 0x7FFFu + ((v.i >> 16) & 1u)) >> 16;   // RNE
    return (u16)r;
}

// ---------------------------------------------------------------------------
// prep kernels (unchanged from v3)
// ---------------------------------------------------------------------------
__global__ __launch_bounds__(256) void prep_x(const float* __restrict__ x,
                                              u16* __restrict__ xpad)
{
    const int idx = blockIdx.x * 256 + threadIdx.x;      // < 262144
    const int t = idx >> 12, b = (idx >> 8) & 15, p = idx & 255;
    const float* src = x + (((size_t)b * 64 + t) * 256 + p) * 6;
    u16x8 v = {};
    v[0] = f2bf(src[0]); v[1] = f2bf(src[1]); v[2] = f2bf(src[2]);
    v[3] = f2bf(src[3]); v[4] = f2bf(src[4]); v[5] = f2bf(src[5]);
    *(u16x8*)(xpad + (size_t)idx * 8) = v;
}

__global__ __launch_bounds__(256) void wtrans0(const float* __restrict__ Wx0,
                                               const float* __restrict__ Wh0,
                                               u16* __restrict__ Wt0)
{
    const int idx = blockIdx.x * 256 + threadIdx.x;      // < 384*960
    const int n = idx / 960, k = idx - n * 960;
    float v = 0.0f;
    if (k < 96) {
        const int q = k >> 3, c = k & 7;
        if (q < 9 && c < 6) v = Wx0[(q * 6 + c) * 384 + n];
    } else {
        v = Wh0[(k - 96) * 384 + n];
    }
    Wt0[idx] = f2bf(v);
}

__global__ __launch_bounds__(256) void wtrans1(const float* __restrict__ Wx1,
                                               const float* __restrict__ Wh1,
                                               u16* __restrict__ Wt1)
{
    const int idx = blockIdx.x * 256 + threadIdx.x;      // < 384*1728
    const int n = idx / 1728, k = idx - n * 1728;
    const float v = (k < 864) ? Wx1[k * 384 + n] : Wh1[(k - 864) * 384 + n];
    Wt1[idx] = f2bf(v);
}

// ---------------------------------------------------------------------------
// paired conv (device): half0 = conv1[t] (KT=1728), half1 = conv0[t+1] (KT=960)
// tile blk: m0=(blk>>2)*64, n0=(blk&3)*96. Lockstep 54 iterations, common
// __syncthreads. Reg-prefetch + double-buffered LDS per half.
// ---------------------------------------------------------------------------
__device__ void conv_pair(int t, int blk, int tidx,
    u16 (&As)[2][2][64][40], u16 (&Bs)[2][2][96][40],
    const u16* __restrict__ xpad, const u16* __restrict__ h0,
    const u16* __restrict__ h1,   const u16* __restrict__ h0bn,
    const u16* __restrict__ Wt0,  const u16* __restrict__ Wt1,
    const float* __restrict__ b0, const float* __restrict__ b1,
    float* __restrict__ gates0,   float* __restrict__ gates1)
{
    const int half = tidx >> 8;           // 0: conv1[t], 1: conv0[t+1]
    const int htid = tidx & 255;
    const bool active = half ? (t < 63) : (t >= 0);

    const int m0 = (blk >> 2) * 64;
    const int n0 = (blk & 3) * 96;
    const int lane = htid & 63;
    const int hw   = htid >> 6;
    const int wm = hw >> 1, wn = hw & 1;
    const int fr = lane & 15, fg = lane >> 4;
    const int arow = htid >> 2, seg = htid & 3;
    const int mg = m0 + arow;
    const int py = (mg >> 4) & 15, px = mg & 15, pb = mg >> 8;

    const int   KT   = half ? 960 : 1728;
    const int   NS0  = half ? 3   : 27;
    const int   MYST = half ? 30  : 54;
    const u16*  Wt   = half ? Wt0 : Wt1;
    const u16*  in1  = half ? h0  : h1;
    const u16*  in0  = half ? (xpad + (size_t)(t + 1) * 32768) : h0bn;
    const float* bias = half ? b0 : b1;
    float*      gout = half ? gates0 : gates1;

    f32x4 acc[2][3];
#pragma unroll
    for (int i = 0; i < 2; ++i)
#pragma unroll
        for (int j = 0; j < 3; ++j) acc[i][j] = (f32x4){0.f, 0.f, 0.f, 0.f};

    u16x8 va, vb0, vb1;
    auto stage = [&](int ks) {
        u16x8 z = {};
        va = z;
        if (half && ks < 3) {
            // layer0 x-part: thread's 16B = all 8 padded channels of tap q
            const int q = ks * 4 + seg;           // 12 taps, q<9 real
            const int qd = q / 3;
            const int yy = py + qd - 1;
            const int xx = px + (q - 3 * qd) - 1;
            if (q < 9 && (unsigned)yy < 16u && (unsigned)xx < 16u)
                va = *(const u16x8*)(in0 + (size_t)((pb << 8) + yy * 16 + xx) * 8);
        } else {
            const int s = (ks < NS0) ? ks : ks - NS0;
            const u16* src = (ks < NS0) ? in0 : in1;
            const int q = s / 3;
            const int c0v = (s - 3 * q) * 32 + seg * 8;
            const int qd = q / 3;
            const int yy = py + qd - 1;
            const int xx = px + (q - 3 * qd) - 1;
            if ((unsigned)yy < 16u && (unsigned)xx < 16u)
                va = *(const u16x8*)(src + (size_t)((pb << 8) + yy * 16 + xx) * 96 + c0v);
        }
        const int koff = ks * 32 + seg * 8;
        vb0 = *(const u16x8*)(Wt + (size_t)(n0 + arow) * KT + koff);
        vb1 = z;
        if (htid < 128)
            vb1 = *(const u16x8*)(Wt + (size_t)(n0 + 64 + arow) * KT + koff);
    };
    auto ldsw = [&](int buf) {
        *(u16x8*)(&As[half][buf][arow][seg * 8]) = va;
        *(u16x8*)(&Bs[half][buf][arow][seg * 8]) = vb0;
        if (htid < 128) *(u16x8*)(&Bs[half][buf][64 + arow][seg * 8]) = vb1;
    };

    if (active) { stage(0); ldsw(0); }
    __syncthreads();

    for (int ks = 0; ks < 54; ++ks) {
        const int cur = ks & 1;
        if (active && ks < MYST) {
            if (ks + 1 < MYST) stage(ks + 1);

            bf16x8 af[2], bq[3];
#pragma unroll
            for (int mf = 0; mf < 2; ++mf)
                af[mf] = *(const bf16x8*)(&As[half][cur][wm * 32 + mf * 16 + fr][fg * 8]);
#pragma unroll
            for (int nf = 0; nf < 3; ++nf)
                bq[nf] = *(const bf16x8*)(&Bs[half][cur][wn * 48 + nf * 16 + fr][fg * 8]);

            __builtin_amdgcn_s_setprio(1);
#pragma unroll
            for (int mf = 0; mf < 2; ++mf)
#pragma unroll
                for (int nf = 0; nf < 3; ++nf)
                    acc[mf][nf] = __builtin_amdgcn_mfma_f32_16x16x32_bf16(
                        af[mf], bq[nf], acc[mf][nf], 0, 0, 0);
            __builtin_amdgcn_s_setprio(0);

            if (ks + 1 < MYST) ldsw(cur ^ 1);
        }
        __syncthreads();   // common site for both halves
    }

    if (active) {
#pragma unroll
        for (int nf = 0; nf < 3; ++nf) {
            const int n = n0 + wn * 48 + nf * 16 + fr;
            const float bi = bias[n];
#pragma unroll
            for (int mf = 0; mf < 2; ++mf) {
                const int mrow = m0 + wm * 32 + mf * 16 + fg * 4;
#pragma unroll
                for (int r = 0; r < 4; ++r)
                    gout[(size_t)(mrow + r) * 384 + n] = acc[mf][nf][r] + bi;
            }
        }
    }
}

// ---------------------------------------------------------------------------
// pointwise item + phase
// ---------------------------------------------------------------------------
__device__ __forceinline__ void pw_item(
    const float* __restrict__ gates, float* __restrict__ cst,
    u16* __restrict__ hraw, u16* __restrict__ hbn,
    const float* __restrict__ gam, const float* __restrict__ bet,
    const float* __restrict__ mu,  const float* __restrict__ var, int i)
{
    const int m = i / 24, f0 = (i - m * 24) * 4;
    const float* gb = gates + (size_t)m * 384 + f0;
    const f32x4 gi = *(const f32x4*)gb;
    const f32x4 gf = *(const f32x4*)(gb + 96);
    const f32x4 gc = *(const f32x4*)(gb + 192);
    const f32x4 go = *(const f32x4*)(gb + 288);
    float* cp = cst + m * 96 + f0;
    f32x4 cc = *(const f32x4*)cp;
    const f32x4 ga = *(const f32x4*)(gam + f0);
    const f32x4 be = *(const f32x4*)(bet + f0);
    const f32x4 mv = *(const f32x4*)(mu + f0);
    const f32x4 vv = *(const f32x4*)(var + f0);

    u16 hu[4], bu[4];
    f32x4 cn;
#pragma unroll
    for (int j = 0; j < 4; ++j) {
        const float i_ = hsig(gi[j]);
        const float f_ = hsig(gf[j]);
        const float o_ = hsig(go[j]);
        const float c_ = f_ * cc[j] + i_ * tanhf(gc[j]);
        const float h_ = o_ * tanhf(c_);
        cn[j] = c_;
        hu[j] = f2bf(h_);
        const float s = ga[j] * rsqrtf(vv[j] + 1e-3f);
        bu[j] = f2bf((h_ - mv[j]) * s + be[j]);
    }
    *(f32x4*)cp = cn;
    uint2 hp; hp.x = hu[0] | ((unsigned)hu[1] << 16); hp.y = hu[2] | ((unsigned)hu[3] << 16);
    uint2 bp; bp.x = bu[0] | ((unsigned)bu[1] << 16); bp.y = bu[2] | ((unsigned)bu[3] << 16);
    *(uint2*)(hraw + (size_t)m * 96 + f0) = hp;
    *(uint2*)(hbn  + (size_t)m * 96 + f0) = bp;
}

__device__ __forceinline__ void phaseB_body(int t, int gtid,
    const float* gates0, const float* gates1,
    float* c0, float* c1, u16* h0, u16* h1, u16* h0bn, u16* hall,
    const float* g0, const float* be0, const float* mu0, const float* v0,
    const float* g1, const float* be1, const float* mu1, const float* v1)
{
    for (int i = gtid; i < 196608; i += 131072) {
        if (i < 98304) {
            if (t >= 0)
                pw_item(gates1, c1, h1, hall + (size_t)t * 393216,
                        g1, be1, mu1, v1, i);
        } else if (t < 63) {
            pw_item(gates0, c0, h0, h0bn, g0, be0, mu0, v0, i - 98304);
        }
    }
}

// ---------------------------------------------------------------------------
// cooperative persistent kernel
// ---------------------------------------------------------------------------
__global__ __launch_bounds__(512, 2) void fused(
    const u16* xpad, u16* h0, u16* h1, float* c0, float* c1, u16* h0bn,
    float* gates0, float* gates1, u16* hall,
    const u16* Wt0, const u16* Wt1,
    const float* b0, const float* b1,
    const float* g0, const float* be0, const float* mu0, const float* v0,
    const float* g1, const float* be1, const float* mu1, const float* v1)
{
    __shared__ u16 As[2][2][64][40];
    __shared__ u16 Bs[2][2][96][40];
    cg::grid_group grid = cg::this_grid();
    const int blk = blockIdx.x;
    const int gtid = blk * 512 + threadIdx.x;    // < 131072

    for (int t = -1; t < 64; ++t) {
        conv_pair(t, blk, threadIdx.x, As, Bs, xpad, h0, h1, h0bn,
                  Wt0, Wt1, b0, b1, gates0, gates1);
        __threadfence();
        grid.sync();
        phaseB_body(t, gtid, gates0, gates1, c0, c1, h0, h1, h0bn, hall,
                    g0, be0, mu0, v0, g1, be1, mu1, v1);
        __threadfence();
        grid.sync();
    }
}

// ---------------------------------------------------------------------------
// fallback per-step kernels (same device code, kernel-boundary sync)
// ---------------------------------------------------------------------------
__global__ __launch_bounds__(512, 2) void stepA(int t,
    const u16* xpad, u16* h0, u16* h1, u16* h0bn,
    const u16* Wt0, const u16* Wt1, const float* b0, const float* b1,
    float* gates0, float* gates1)
{
    __shared__ u16 As[2][2][64][40];
    __shared__ u16 Bs[2][2][96][40];
    conv_pair(t, blockIdx.x, threadIdx.x, As, Bs, xpad, h0, h1, h0bn,
              Wt0, Wt1, b0, b1, gates0, gates1);
}

__global__ __launch_bounds__(256) void stepB(int t,
    const float* gates0, const float* gates1,
    float* c0, float* c1, u16* h0, u16* h1, u16* h0bn, u16* hall,
    const float* g0, const float* be0, const float* mu0, const float* v0,
    const float* g1, const float* be1, const float* mu1, const float* v1)
{
    const int gtid = blockIdx.x * 256 + threadIdx.x;   // 512 blocks -> <131072
    phaseB_body(t, gtid, gates0, gates1, c0, c1, h0, h1, h0bn, hall,
                g0, be0, mu0, v0, g1, be1, mu1, v1);
}

// ---------------------------------------------------------------------------
// dense tail (unchanged)
// ---------------------------------------------------------------------------
__global__ void dense_partial(const u16* __restrict__ hall,
                              const float* __restrict__ Wd,
                              float* __restrict__ partial)
{
    const int k0 = blockIdx.x * 2048;
    const int tt = k0 / 24576;
    const int r0 = k0 - tt * 24576;
    const int t  = threadIdx.x;          // 0..159
    const int b  = t / 10;
    const int nc = t - b * 10;
    const u16* hp = hall + (size_t)(tt * 16 + b) * 24576 + r0;
    const float* wp = Wd + (size_t)k0 * 10 + nc;
    float acc = 0.0f;
    for (int j = 0; j < 2048; j += 8) {
        const u16x8 hv = *(const u16x8*)(hp + j);
#pragma unroll
        for (int u = 0; u < 8; ++u)
            acc = fmaf(bf2f(hv[u]), wp[(size_t)(j + u) * 10], acc);
    }
    partial[blockIdx.x * 160 + t] = acc;
}

__global__ void dense_reduce(const float* __restrict__ partial,
                             const float* __restrict__ bd,
                             float* __restrict__ out)
{
    const int t = threadIdx.x;           // 0..159
    const int nc = t - (t / 10) * 10;
    float acc = bd[nc];
    for (int p = 0; p < 768; ++p) acc += partial[p * 160 + t];
    out[t] = acc;
}

// ---------------------------------------------------------------------------
extern "C" void kernel_launch(void* const* d_in, const int* in_sizes, int n_in,
                              void* d_out, int out_size, void* d_ws, size_t ws_size,
                              hipStream_t stream)
{
    const float* x    = (const float*)d_in[0];
    const float* Wx0  = (const float*)d_in[1];
    const float* Wh0  = (const float*)d_in[2];
    const float* b0p  = (const float*)d_in[3];
    const float* g0p  = (const float*)d_in[4];
    const float* be0p = (const float*)d_in[5];
    const float* mu0p = (const float*)d_in[6];
    const float* v0p  = (const float*)d_in[7];
    const float* Wx1  = (const float*)d_in[8];
    const float* Wh1  = (const float*)d_in[9];
    const float* b1p  = (const float*)d_in[10];
    const float* g1p  = (const float*)d_in[11];
    const float* be1p = (const float*)d_in[12];
    const float* mu1p = (const float*)d_in[13];
    const float* v1p  = (const float*)d_in[14];
    const float* Wd   = (const float*)d_in[15];
    const float* bd   = (const float*)d_in[16];
    float* out = (float*)d_out;

    char* base = (char*)d_ws;
    u16*   h0     = (u16*)(base);                      //   786432 B
    u16*   h1     = (u16*)(base + 786432);             //   786432 B
    float* c0     = (float*)(base + 1572864);          //  1572864 B
    float* c1     = (float*)(base + 3145728);          //  1572864 B
    u16*   h0bn   = (u16*)(base + 4718592);            //   786432 B
    float* gates0 = (float*)(base + 5505024);          //  6291456 B
    float* gates1 = (float*)(base + 11796480);         //  6291456 B
    u16*   xpad   = (u16*)(base + 18087936);           //  4194304 B
    u16*   Wt0    = (u16*)(base + 22282240);           //   737280 B
    u16*   Wt1    = (u16*)(base + 23019520);           //  1327104 B
    u16*   hall   = (u16*)(base + 24346624);           // 50331648 B
    float* part   = (float*)(base + 74678272);         //   491520 B

    hipMemsetAsync(base, 0, 4718592, stream);          // h0,h1,c0,c1,h0bn = 0

    prep_x <<<1024, 256, 0, stream>>>(x, xpad);
    wtrans0<<<1440, 256, 0, stream>>>(Wx0, Wh0, Wt0);
    wtrans1<<<2592, 256, 0, stream>>>(Wx1, Wh1, Wt1);

    void* args[] = {
        (void*)&xpad, (void*)&h0, (void*)&h1, (void*)&c0, (void*)&c1,
        (void*)&h0bn, (void*)&gates0, (void*)&gates1, (void*)&hall,
        (void*)&Wt0, (void*)&Wt1, (void*)&b0p, (void*)&b1p,
        (void*)&g0p, (void*)&be0p, (void*)&mu0p, (void*)&v0p,
        (void*)&g1p, (void*)&be1p, (void*)&mu1p, (void*)&v1p
    };
    hipError_t ce = hipLaunchCooperativeKernel((void*)fused, dim3(256),
                                               dim3(512), args, 0, stream);
    if (ce != hipSuccess) {
        (void)hipGetLastError();   // clear sticky error, use fallback path
        for (int t = -1; t < 64; ++t) {
            stepA<<<256, 512, 0, stream>>>(t, xpad, h0, h1, h0bn,
                                           Wt0, Wt1, b0p, b1p, gates0, gates1);
            stepB<<<512, 256, 0, stream>>>(t, gates0, gates1, c0, c1, h0, h1,
                                           h0bn, hall, g0p, be0p, mu0p, v0p,
                                           g1p, be1p, mu1p, v1p);
        }
    }

    dense_partial<<<768, 160, 0, stream>>>(hall, Wd, part);
    dense_reduce <<<1, 160, 0, stream>>>(part, bd, out);
}

// Round 6
// 6955.225 us; speedup vs baseline: 2.0510x; 2.0510x over previous
//
#include <hip/hip_runtime.h>
#include <math.h>

// ImuModel v6: persistent ConvLSTM, cooperative-launched 256 blocks x 512 thr,
// hand-rolled monotonic atomic grid barrier (grid.sync measured at ~105 us on
// MI355X — the v5 kernel was 95% barrier). 2 barriers per timestep, 130 total.
// Block = two 256-thread halves in lockstep: half0 = conv1[t] tile,
// half1 = conv0[t+1] tile. Fallback: per-step launches if coop launch fails.

typedef __attribute__((ext_vector_type(8))) short     bf16x8;
typedef __attribute__((ext_vector_type(8))) unsigned short u16x8;
typedef __attribute__((ext_vector_type(4))) float     f32x4;
typedef unsigned short u16;

__device__ __forceinline__ float hsig(float x) {
    return fminf(fmaxf(0.2f * x + 0.5f, 0.0f), 1.0f);
}
__device__ __forceinline__ float bf2f(u16 u) {
    union { unsigned int i; float f; } v; v.i = ((unsigned int)u) << 16; return v.f;
}
__device__ __forceinline__ u16 f2bf(float f) {
    union { float f; unsigned int i; } v; v.f = f;
    unsigned int r = (v.i + 0x7FFFu + ((v.i >> 16) & 1u)) >> 16;   // RNE
    return (u16)r;
}

// monotonic grid barrier: k-th barrier waits for cnt >= k*256
__device__ __forceinline__ void gridbar(unsigned* cnt, unsigned target) {
    __syncthreads();                  // all block stores drained to local L2
    if (threadIdx.x == 0) {
        __threadfence();              // release: writeback local L2 device-wide
        __hip_atomic_fetch_add(cnt, 1u, __ATOMIC_RELEASE,
                               __HIP_MEMORY_SCOPE_AGENT);
        while (__hip_atomic_load(cnt, __ATOMIC_ACQUIRE,
                                 __HIP_MEMORY_SCOPE_AGENT) < target)
            __builtin_amdgcn_s_sleep(8);
        __threadfence();              // acquire: invalidate local caches
    }
    __syncthreads();
}

// ---------------------------------------------------------------------------
// prep kernels (unchanged)
// ---------------------------------------------------------------------------
__global__ __launch_bounds__(256) void prep_x(const float* __restrict__ x,
                                              u16* __restrict__ xpad)
{
    const int idx = blockIdx.x * 256 + threadIdx.x;      // < 262144
    const int t = idx >> 12, b = (idx >> 8) & 15, p = idx & 255;
    const float* src = x + (((size_t)b * 64 + t) * 256 + p) * 6;
    u16x8 v = {};
    v[0] = f2bf(src[0]); v[1] = f2bf(src[1]); v[2] = f2bf(src[2]);
    v[3] = f2bf(src[3]); v[4] = f2bf(src[4]); v[5] = f2bf(src[5]);
    *(u16x8*)(xpad + (size_t)idx * 8) = v;
}

__global__ __launch_bounds__(256) void wtrans0(const float* __restrict__ Wx0,
                                               const float* __restrict__ Wh0,
                                               u16* __restrict__ Wt0)
{
    const int idx = blockIdx.x * 256 + threadIdx.x;      // < 384*960
    const int n = idx / 960, k = idx - n * 960;
    float v = 0.0f;
    if (k < 96) {
        const int q = k >> 3, c = k & 7;
        if (q < 9 && c < 6) v = Wx0[(q * 6 + c) * 384 + n];
    } else {
        v = Wh0[(k - 96) * 384 + n];
    }
    Wt0[idx] = f2bf(v);
}

__global__ __launch_bounds__(256) void wtrans1(const float* __restrict__ Wx1,
                                               const float* __restrict__ Wh1,
                                               u16* __restrict__ Wt1)
{
    const int idx = blockIdx.x * 256 + threadIdx.x;      // < 384*1728
    const int n = idx / 1728, k = idx - n * 1728;
    const float v = (k < 864) ? Wx1[k * 384 + n] : Wh1[(k - 864) * 384 + n];
    Wt1[idx] = f2bf(v);
}

// ---------------------------------------------------------------------------
// paired conv (device): half0 = conv1[t] (KT=1728), half1 = conv0[t+1] (KT=960)
// tile blk: m0=(blk>>2)*64, n0=(blk&3)*96. Lockstep 54 iterations, common
// __syncthreads. Reg-prefetch + double-buffered LDS per half.
// ---------------------------------------------------------------------------
__device__ void conv_pair(int t, int blk, int tidx,
    u16 (&As)[2][2][64][40], u16 (&Bs)[2][2][96][40],
    const u16* __restrict__ xpad, const u16* __restrict__ h0,
    const u16* __restrict__ h1,   const u16* __restrict__ h0bn,
    const u16* __restrict__ Wt0,  const u16* __restrict__ Wt1,
    const float* __restrict__ b0, const float* __restrict__ b1,
    float* __restrict__ gates0,   float* __restrict__ gates1)
{
    const int half = tidx >> 8;           // 0: conv1[t], 1: conv0[t+1]
    const int htid = tidx & 255;
    const bool active = half ? (t < 63) : (t >= 0);

    const int m0 = (blk >> 2) * 64;
    const int n0 = (blk & 3) * 96;
    const int lane = htid & 63;
    const int hw   = htid >> 6;
    const int wm = hw >> 1, wn = hw & 1;
    const int fr = lane & 15, fg = lane >> 4;
    const int arow = htid >> 2, seg = htid & 3;
    const int mg = m0 + arow;
    const int py = (mg >> 4) & 15, px = mg & 15, pb = mg >> 8;

    const int   KT   = half ? 960 : 1728;
    const int   NS0  = half ? 3   : 27;
    const int   MYST = half ? 30  : 54;
    const u16*  Wt   = half ? Wt0 : Wt1;
    const u16*  in1  = half ? h0  : h1;
    const u16*  in0  = half ? (xpad + (size_t)(t + 1) * 32768) : h0bn;
    const float* bias = half ? b0 : b1;
    float*      gout = half ? gates0 : gates1;

    f32x4 acc[2][3];
#pragma unroll
    for (int i = 0; i < 2; ++i)
#pragma unroll
        for (int j = 0; j < 3; ++j) acc[i][j] = (f32x4){0.f, 0.f, 0.f, 0.f};

    u16x8 va, vb0, vb1;
    auto stage = [&](int ks) {
        u16x8 z = {};
        va = z;
        if (half && ks < 3) {
            // layer0 x-part: thread's 16B = all 8 padded channels of tap q
            const int q = ks * 4 + seg;           // 12 taps, q<9 real
            const int qd = q / 3;
            const int yy = py + qd - 1;
            const int xx = px + (q - 3 * qd) - 1;
            if (q < 9 && (unsigned)yy < 16u && (unsigned)xx < 16u)
                va = *(const u16x8*)(in0 + (size_t)((pb << 8) + yy * 16 + xx) * 8);
        } else {
            const int s = (ks < NS0) ? ks : ks - NS0;
            const u16* src = (ks < NS0) ? in0 : in1;
            const int q = s / 3;
            const int c0v = (s - 3 * q) * 32 + seg * 8;
            const int qd = q / 3;
            const int yy = py + qd - 1;
            const int xx = px + (q - 3 * qd) - 1;
            if ((unsigned)yy < 16u && (unsigned)xx < 16u)
                va = *(const u16x8*)(src + (size_t)((pb << 8) + yy * 16 + xx) * 96 + c0v);
        }
        const int koff = ks * 32 + seg * 8;
        vb0 = *(const u16x8*)(Wt + (size_t)(n0 + arow) * KT + koff);
        vb1 = z;
        if (htid < 128)
            vb1 = *(const u16x8*)(Wt + (size_t)(n0 + 64 + arow) * KT + koff);
    };
    auto ldsw = [&](int buf) {
        *(u16x8*)(&As[half][buf][arow][seg * 8]) = va;
        *(u16x8*)(&Bs[half][buf][arow][seg * 8]) = vb0;
        if (htid < 128) *(u16x8*)(&Bs[half][buf][64 + arow][seg * 8]) = vb1;
    };

    if (active) { stage(0); ldsw(0); }
    __syncthreads();

    for (int ks = 0; ks < 54; ++ks) {
        const int cur = ks & 1;
        if (active && ks < MYST) {
            if (ks + 1 < MYST) stage(ks + 1);

            bf16x8 af[2], bq[3];
#pragma unroll
            for (int mf = 0; mf < 2; ++mf)
                af[mf] = *(const bf16x8*)(&As[half][cur][wm * 32 + mf * 16 + fr][fg * 8]);
#pragma unroll
            for (int nf = 0; nf < 3; ++nf)
                bq[nf] = *(const bf16x8*)(&Bs[half][cur][wn * 48 + nf * 16 + fr][fg * 8]);

            __builtin_amdgcn_s_setprio(1);
#pragma unroll
            for (int mf = 0; mf < 2; ++mf)
#pragma unroll
                for (int nf = 0; nf < 3; ++nf)
                    acc[mf][nf] = __builtin_amdgcn_mfma_f32_16x16x32_bf16(
                        af[mf], bq[nf], acc[mf][nf], 0, 0, 0);
            __builtin_amdgcn_s_setprio(0);

            if (ks + 1 < MYST) ldsw(cur ^ 1);
        }
        __syncthreads();   // common site for both halves
    }

    if (active) {
#pragma unroll
        for (int nf = 0; nf < 3; ++nf) {
            const int n = n0 + wn * 48 + nf * 16 + fr;
            const float bi = bias[n];
#pragma unroll
            for (int mf = 0; mf < 2; ++mf) {
                const int mrow = m0 + wm * 32 + mf * 16 + fg * 4;
#pragma unroll
                for (int r = 0; r < 4; ++r)
                    gout[(size_t)(mrow + r) * 384 + n] = acc[mf][nf][r] + bi;
            }
        }
    }
}

// ---------------------------------------------------------------------------
// pointwise item + phase
// ---------------------------------------------------------------------------
__device__ __forceinline__ void pw_item(
    const float* __restrict__ gates, float* __restrict__ cst,
    u16* __restrict__ hraw, u16* __restrict__ hbn,
    const float* __restrict__ gam, const float* __restrict__ bet,
    const float* __restrict__ mu,  const float* __restrict__ var, int i)
{
    const int m = i / 24, f0 = (i - m * 24) * 4;
    const float* gb = gates + (size_t)m * 384 + f0;
    const f32x4 gi = *(const f32x4*)gb;
    const f32x4 gf = *(const f32x4*)(gb + 96);
    const f32x4 gc = *(const f32x4*)(gb + 192);
    const f32x4 go = *(const f32x4*)(gb + 288);
    float* cp = cst + m * 96 + f0;
    f32x4 cc = *(const f32x4*)cp;
    const f32x4 ga = *(const f32x4*)(gam + f0);
    const f32x4 be = *(const f32x4*)(bet + f0);
    const f32x4 mv = *(const f32x4*)(mu + f0);
    const f32x4 vv = *(const f32x4*)(var + f0);

    u16 hu[4], bu[4];
    f32x4 cn;
#pragma unroll
    for (int j = 0; j < 4; ++j) {
        const float i_ = hsig(gi[j]);
        const float f_ = hsig(gf[j]);
        const float o_ = hsig(go[j]);
        const float c_ = f_ * cc[j] + i_ * tanhf(gc[j]);
        const float h_ = o_ * tanhf(c_);
        cn[j] = c_;
        hu[j] = f2bf(h_);
        const float s = ga[j] * rsqrtf(vv[j] + 1e-3f);
        bu[j] = f2bf((h_ - mv[j]) * s + be[j]);
    }
    *(f32x4*)cp = cn;
    uint2 hp; hp.x = hu[0] | ((unsigned)hu[1] << 16); hp.y = hu[2] | ((unsigned)hu[3] << 16);
    uint2 bp; bp.x = bu[0] | ((unsigned)bu[1] << 16); bp.y = bu[2] | ((unsigned)bu[3] << 16);
    *(uint2*)(hraw + (size_t)m * 96 + f0) = hp;
    *(uint2*)(hbn  + (size_t)m * 96 + f0) = bp;
}

__device__ __forceinline__ void phaseB_body(int t, int gtid,
    const float* gates0, const float* gates1,
    float* c0, float* c1, u16* h0, u16* h1, u16* h0bn, u16* hall,
    const float* g0, const float* be0, const float* mu0, const float* v0,
    const float* g1, const float* be1, const float* mu1, const float* v1)
{
    for (int i = gtid; i < 196608; i += 131072) {
        if (i < 98304) {
            if (t >= 0)
                pw_item(gates1, c1, h1, hall + (size_t)t * 393216,
                        g1, be1, mu1, v1, i);
        } else if (t < 63) {
            pw_item(gates0, c0, h0, h0bn, g0, be0, mu0, v0, i - 98304);
        }
    }
}

// ---------------------------------------------------------------------------
// persistent kernel with hand-rolled barrier
// ---------------------------------------------------------------------------
__global__ __launch_bounds__(512, 2) void fused(
    unsigned* bcnt,
    const u16* xpad, u16* h0, u16* h1, float* c0, float* c1, u16* h0bn,
    float* gates0, float* gates1, u16* hall,
    const u16* Wt0, const u16* Wt1,
    const float* b0, const float* b1,
    const float* g0, const float* be0, const float* mu0, const float* v0,
    const float* g1, const float* be1, const float* mu1, const float* v1)
{
    __shared__ u16 As[2][2][64][40];
    __shared__ u16 Bs[2][2][96][40];
    const int blk = blockIdx.x;
    const int gtid = blk * 512 + threadIdx.x;    // < 131072

    unsigned bar = 0;
    for (int t = -1; t < 64; ++t) {
        conv_pair(t, blk, threadIdx.x, As, Bs, xpad, h0, h1, h0bn,
                  Wt0, Wt1, b0, b1, gates0, gates1);
        gridbar(bcnt, (++bar) * 256u);
        phaseB_body(t, gtid, gates0, gates1, c0, c1, h0, h1, h0bn, hall,
                    g0, be0, mu0, v0, g1, be1, mu1, v1);
        gridbar(bcnt, (++bar) * 256u);
    }
}

// ---------------------------------------------------------------------------
// fallback per-step kernels (same device code, kernel-boundary sync)
// ---------------------------------------------------------------------------
__global__ __launch_bounds__(512, 2) void stepA(int t,
    const u16* xpad, u16* h0, u16* h1, u16* h0bn,
    const u16* Wt0, const u16* Wt1, const float* b0, const float* b1,
    float* gates0, float* gates1)
{
    __shared__ u16 As[2][2][64][40];
    __shared__ u16 Bs[2][2][96][40];
    conv_pair(t, blockIdx.x, threadIdx.x, As, Bs, xpad, h0, h1, h0bn,
              Wt0, Wt1, b0, b1, gates0, gates1);
}

__global__ __launch_bounds__(256) void stepB(int t,
    const float* gates0, const float* gates1,
    float* c0, float* c1, u16* h0, u16* h1, u16* h0bn, u16* hall,
    const float* g0, const float* be0, const float* mu0, const float* v0,
    const float* g1, const float* be1, const float* mu1, const float* v1)
{
    const int gtid = blockIdx.x * 256 + threadIdx.x;   // 512 blocks -> <131072
    phaseB_body(t, gtid, gates0, gates1, c0, c1, h0, h1, h0bn, hall,
                g0, be0, mu0, v0, g1, be1, mu1, v1);
}

// ---------------------------------------------------------------------------
// dense tail (unchanged)
// ---------------------------------------------------------------------------
__global__ void dense_partial(const u16* __restrict__ hall,
                              const float* __restrict__ Wd,
                              float* __restrict__ partial)
{
    const int k0 = blockIdx.x * 2048;
    const int tt = k0 / 24576;
    const int r0 = k0 - tt * 24576;
    const int t  = threadIdx.x;          // 0..159
    const int b  = t / 10;
    const int nc = t - b * 10;
    const u16* hp = hall + (size_t)(tt * 16 + b) * 24576 + r0;
    const float* wp = Wd + (size_t)k0 * 10 + nc;
    float acc = 0.0f;
    for (int j = 0; j < 2048; j += 8) {
        const u16x8 hv = *(const u16x8*)(hp + j);
#pragma unroll
        for (int u = 0; u < 8; ++u)
            acc = fmaf(bf2f(hv[u]), wp[(size_t)(j + u) * 10], acc);
    }
    partial[blockIdx.x * 160 + t] = acc;
}

__global__ void dense_reduce(const float* __restrict__ partial,
                             const float* __restrict__ bd,
                             float* __restrict__ out)
{
    const int t = threadIdx.x;           // 0..159
    const int nc = t - (t / 10) * 10;
    float acc = bd[nc];
    for (int p = 0; p < 768; ++p) acc += partial[p * 160 + t];
    out[t] = acc;
}

// ---------------------------------------------------------------------------
extern "C" void kernel_launch(void* const* d_in, const int* in_sizes, int n_in,
                              void* d_out, int out_size, void* d_ws, size_t ws_size,
                              hipStream_t stream)
{
    const float* x    = (const float*)d_in[0];
    const float* Wx0  = (const float*)d_in[1];
    const float* Wh0  = (const float*)d_in[2];
    const float* b0p  = (const float*)d_in[3];
    const float* g0p  = (const float*)d_in[4];
    const float* be0p = (const float*)d_in[5];
    const float* mu0p = (const float*)d_in[6];
    const float* v0p  = (const float*)d_in[7];
    const float* Wx1  = (const float*)d_in[8];
    const float* Wh1  = (const float*)d_in[9];
    const float* b1p  = (const float*)d_in[10];
    const float* g1p  = (const float*)d_in[11];
    const float* be1p = (const float*)d_in[12];
    const float* mu1p = (const float*)d_in[13];
    const float* v1p  = (const float*)d_in[14];
    const float* Wd   = (const float*)d_in[15];
    const float* bd   = (const float*)d_in[16];
    float* out = (float*)d_out;

    char* base = (char*)d_ws;
    u16*   h0     = (u16*)(base);                      //   786432 B
    u16*   h1     = (u16*)(base + 786432);             //   786432 B
    float* c0     = (float*)(base + 1572864);          //  1572864 B
    float* c1     = (float*)(base + 3145728);          //  1572864 B
    u16*   h0bn   = (u16*)(base + 4718592);            //   786432 B
    float* gates0 = (float*)(base + 5505024);          //  6291456 B
    float* gates1 = (float*)(base + 11796480);         //  6291456 B
    u16*   xpad   = (u16*)(base + 18087936);           //  4194304 B
    u16*   Wt0    = (u16*)(base + 22282240);           //   737280 B
    u16*   Wt1    = (u16*)(base + 23019520);           //  1327104 B
    u16*   hall   = (u16*)(base + 24346624);           // 50331648 B
    float* part   = (float*)(base + 74678272);         //   491520 B
    unsigned* bcnt = (unsigned*)(base + 75169792);     //      256 B

    hipMemsetAsync(base, 0, 4718592, stream);          // h0,h1,c0,c1,h0bn = 0
    hipMemsetAsync(bcnt, 0, 256, stream);              // barrier counter = 0

    prep_x <<<1024, 256, 0, stream>>>(x, xpad);
    wtrans0<<<1440, 256, 0, stream>>>(Wx0, Wh0, Wt0);
    wtrans1<<<2592, 256, 0, stream>>>(Wx1, Wh1, Wt1);

    void* args[] = {
        (void*)&bcnt,
        (void*)&xpad, (void*)&h0, (void*)&h1, (void*)&c0, (void*)&c1,
        (void*)&h0bn, (void*)&gates0, (void*)&gates1, (void*)&hall,
        (void*)&Wt0, (void*)&Wt1, (void*)&b0p, (void*)&b1p,
        (void*)&g0p, (void*)&be0p, (void*)&mu0p, (void*)&v0p,
        (void*)&g1p, (void*)&be1p, (void*)&mu1p, (void*)&v1p
    };
    hipError_t ce = hipLaunchCooperativeKernel((void*)fused, dim3(256),
                                               dim3(512), args, 0, stream);
    if (ce != hipSuccess) {
        (void)hipGetLastError();   // clear sticky error, use fallback path
        for (int t = -1; t < 64; ++t) {
            stepA<<<256, 512, 0, stream>>>(t, xpad, h0, h1, h0bn,
                                           Wt0, Wt1, b0p, b1p, gates0, gates1);
            stepB<<<512, 256, 0, stream>>>(t, gates0, gates1, c0, c1, h0, h1,
                                           h0bn, hall, g0p, be0p, mu0p, v0p,
                                           g1p, be1p, mu1p, v1p);
        }
    }

    dense_partial<<<768, 160, 0, stream>>>(hall, Wd, part);
    dense_reduce <<<1, 160, 0, stream>>>(part, bd, out);
}

// Round 7
// 4360.481 us; speedup vs baseline: 3.2714x; 1.5951x over previous
//
#include <hip/hip_runtime.h>
#include <math.h>

// ImuModel v7: persistent ConvLSTM (coop 256 blk x 512 thr) with a fast
// two-level grid barrier. v6's single-counter barrier measured ~45us/barrier
// (256 remote RMWs on one line serialize); v7: 64 spaced arrival counters
// (RELAXED adds) + block0-wave0 aggregation + epoch broadcast + split
// release/acquire fences. 2 barriers per step, 130 total.

typedef __attribute__((ext_vector_type(8))) short     bf16x8;
typedef __attribute__((ext_vector_type(8))) unsigned short u16x8;
typedef __attribute__((ext_vector_type(4))) float     f32x4;
typedef unsigned short u16;

__device__ __forceinline__ float hsig(float x) {
    return fminf(fmaxf(0.2f * x + 0.5f, 0.0f), 1.0f);
}
__device__ __forceinline__ float bf2f(u16 u) {
    union { unsigned int i; float f; } v; v.i = ((unsigned int)u) << 16; return v.f;
}
__device__ __forceinline__ u16 f2bf(float f) {
    union { float f; unsigned int i; } v; v.f = f;
    unsigned int r = (v.i + 0x7FFFu + ((v.i >> 16) & 1u)) >> 16;   // RNE
    return (u16)r;
}

// two-level grid barrier, monotonic epoch k (1-based), 256 blocks fixed.
// ctrs: 64 counters spaced 64 u32 (256B) apart. epoch: single u32.
__device__ __forceinline__ void gridbar(unsigned* ctrs, unsigned* epoch,
                                        unsigned k, int blk)
{
    __syncthreads();                      // block stores drained to local L2
    if (threadIdx.x == 0) {
        __builtin_amdgcn_fence(__ATOMIC_RELEASE, "agent");   // wbl2, waits
        __hip_atomic_fetch_add(ctrs + (blk & 63) * 64, 1u,
                               __ATOMIC_RELAXED, __HIP_MEMORY_SCOPE_AGENT);
    }
    if (blk == 0 && threadIdx.x < 64) {
        const unsigned target = k * 256u;
        unsigned sum;
        do {
            unsigned v = __hip_atomic_load(ctrs + threadIdx.x * 64,
                                           __ATOMIC_RELAXED,
                                           __HIP_MEMORY_SCOPE_AGENT);
            sum = v;
#pragma unroll
            for (int m = 1; m < 64; m <<= 1)
                sum += __shfl_xor(sum, m, 64);
            if (sum < target) __builtin_amdgcn_s_sleep(2);
        } while (sum < target);
        if (threadIdx.x == 0)
            __hip_atomic_store(epoch, k, __ATOMIC_RELAXED,
                               __HIP_MEMORY_SCOPE_AGENT);
    }
    if (threadIdx.x == 0) {
        while (__hip_atomic_load(epoch, __ATOMIC_RELAXED,
                                 __HIP_MEMORY_SCOPE_AGENT) < k)
            __builtin_amdgcn_s_sleep(4);
        __builtin_amdgcn_fence(__ATOMIC_ACQUIRE, "agent");   // inv stale
    }
    __syncthreads();
}

// ---------------------------------------------------------------------------
// prep kernels (unchanged)
// ---------------------------------------------------------------------------
__global__ __launch_bounds__(256) void prep_x(const float* __restrict__ x,
                                              u16* __restrict__ xpad)
{
    const int idx = blockIdx.x * 256 + threadIdx.x;      // < 262144
    const int t = idx >> 12, b = (idx >> 8) & 15, p = idx & 255;
    const float* src = x + (((size_t)b * 64 + t) * 256 + p) * 6;
    u16x8 v = {};
    v[0] = f2bf(src[0]); v[1] = f2bf(src[1]); v[2] = f2bf(src[2]);
    v[3] = f2bf(src[3]); v[4] = f2bf(src[4]); v[5] = f2bf(src[5]);
    *(u16x8*)(xpad + (size_t)idx * 8) = v;
}

__global__ __launch_bounds__(256) void wtrans0(const float* __restrict__ Wx0,
                                               const float* __restrict__ Wh0,
                                               u16* __restrict__ Wt0)
{
    const int idx = blockIdx.x * 256 + threadIdx.x;      // < 384*960
    const int n = idx / 960, k = idx - n * 960;
    float v = 0.0f;
    if (k < 96) {
        const int q = k >> 3, c = k & 7;
        if (q < 9 && c < 6) v = Wx0[(q * 6 + c) * 384 + n];
    } else {
        v = Wh0[(k - 96) * 384 + n];
    }
    Wt0[idx] = f2bf(v);
}

__global__ __launch_bounds__(256) void wtrans1(const float* __restrict__ Wx1,
                                               const float* __restrict__ Wh1,
                                               u16* __restrict__ Wt1)
{
    const int idx = blockIdx.x * 256 + threadIdx.x;      // < 384*1728
    const int n = idx / 1728, k = idx - n * 1728;
    const float v = (k < 864) ? Wx1[k * 384 + n] : Wh1[(k - 864) * 384 + n];
    Wt1[idx] = f2bf(v);
}

// ---------------------------------------------------------------------------
// paired conv (device): half0 = conv1[t] (KT=1728), half1 = conv0[t+1] (KT=960)
// ---------------------------------------------------------------------------
__device__ void conv_pair(int t, int blk, int tidx,
    u16 (&As)[2][2][64][40], u16 (&Bs)[2][2][96][40],
    const u16* __restrict__ xpad, const u16* __restrict__ h0,
    const u16* __restrict__ h1,   const u16* __restrict__ h0bn,
    const u16* __restrict__ Wt0,  const u16* __restrict__ Wt1,
    const float* __restrict__ b0, const float* __restrict__ b1,
    float* __restrict__ gates0,   float* __restrict__ gates1)
{
    const int half = tidx >> 8;           // 0: conv1[t], 1: conv0[t+1]
    const int htid = tidx & 255;
    const bool active = half ? (t < 63) : (t >= 0);

    const int m0 = (blk >> 2) * 64;
    const int n0 = (blk & 3) * 96;
    const int lane = htid & 63;
    const int hw   = htid >> 6;
    const int wm = hw >> 1, wn = hw & 1;
    const int fr = lane & 15, fg = lane >> 4;
    const int arow = htid >> 2, seg = htid & 3;
    const int mg = m0 + arow;
    const int py = (mg >> 4) & 15, px = mg & 15, pb = mg >> 8;

    const int   KT   = half ? 960 : 1728;
    const int   NS0  = half ? 3   : 27;
    const int   MYST = half ? 30  : 54;
    const u16*  Wt   = half ? Wt0 : Wt1;
    const u16*  in1  = half ? h0  : h1;
    const u16*  in0  = half ? (xpad + (size_t)(t + 1) * 32768) : h0bn;
    const float* bias = half ? b0 : b1;
    float*      gout = half ? gates0 : gates1;

    f32x4 acc[2][3];
#pragma unroll
    for (int i = 0; i < 2; ++i)
#pragma unroll
        for (int j = 0; j < 3; ++j) acc[i][j] = (f32x4){0.f, 0.f, 0.f, 0.f};

    u16x8 va, vb0, vb1;
    auto stage = [&](int ks) {
        u16x8 z = {};
        va = z;
        if (half && ks < 3) {
            const int q = ks * 4 + seg;           // 12 taps, q<9 real
            const int qd = q / 3;
            const int yy = py + qd - 1;
            const int xx = px + (q - 3 * qd) - 1;
            if (q < 9 && (unsigned)yy < 16u && (unsigned)xx < 16u)
                va = *(const u16x8*)(in0 + (size_t)((pb << 8) + yy * 16 + xx) * 8);
        } else {
            const int s = (ks < NS0) ? ks : ks - NS0;
            const u16* src = (ks < NS0) ? in0 : in1;
            const int q = s / 3;
            const int c0v = (s - 3 * q) * 32 + seg * 8;
            const int qd = q / 3;
            const int yy = py + qd - 1;
            const int xx = px + (q - 3 * qd) - 1;
            if ((unsigned)yy < 16u && (unsigned)xx < 16u)
                va = *(const u16x8*)(src + (size_t)((pb << 8) + yy * 16 + xx) * 96 + c0v);
        }
        const int koff = ks * 32 + seg * 8;
        vb0 = *(const u16x8*)(Wt + (size_t)(n0 + arow) * KT + koff);
        vb1 = z;
        if (htid < 128)
            vb1 = *(const u16x8*)(Wt + (size_t)(n0 + 64 + arow) * KT + koff);
    };
    auto ldsw = [&](int buf) {
        *(u16x8*)(&As[half][buf][arow][seg * 8]) = va;
        *(u16x8*)(&Bs[half][buf][arow][seg * 8]) = vb0;
        if (htid < 128) *(u16x8*)(&Bs[half][buf][64 + arow][seg * 8]) = vb1;
    };

    if (active) { stage(0); ldsw(0); }
    __syncthreads();

    for (int ks = 0; ks < 54; ++ks) {
        const int cur = ks & 1;
        if (active && ks < MYST) {
            if (ks + 1 < MYST) stage(ks + 1);

            bf16x8 af[2], bq[3];
#pragma unroll
            for (int mf = 0; mf < 2; ++mf)
                af[mf] = *(const bf16x8*)(&As[half][cur][wm * 32 + mf * 16 + fr][fg * 8]);
#pragma unroll
            for (int nf = 0; nf < 3; ++nf)
                bq[nf] = *(const bf16x8*)(&Bs[half][cur][wn * 48 + nf * 16 + fr][fg * 8]);

            __builtin_amdgcn_s_setprio(1);
#pragma unroll
            for (int mf = 0; mf < 2; ++mf)
#pragma unroll
                for (int nf = 0; nf < 3; ++nf)
                    acc[mf][nf] = __builtin_amdgcn_mfma_f32_16x16x32_bf16(
                        af[mf], bq[nf], acc[mf][nf], 0, 0, 0);
            __builtin_amdgcn_s_setprio(0);

            if (ks + 1 < MYST) ldsw(cur ^ 1);
        }
        __syncthreads();   // common site for both halves
    }

    if (active) {
#pragma unroll
        for (int nf = 0; nf < 3; ++nf) {
            const int n = n0 + wn * 48 + nf * 16 + fr;
            const float bi = bias[n];
#pragma unroll
            for (int mf = 0; mf < 2; ++mf) {
                const int mrow = m0 + wm * 32 + mf * 16 + fg * 4;
#pragma unroll
                for (int r = 0; r < 4; ++r)
                    gout[(size_t)(mrow + r) * 384 + n] = acc[mf][nf][r] + bi;
            }
        }
    }
}

// ---------------------------------------------------------------------------
// pointwise
// ---------------------------------------------------------------------------
__device__ __forceinline__ void pw_item(
    const float* __restrict__ gates, float* __restrict__ cst,
    u16* __restrict__ hraw, u16* __restrict__ hbn,
    const float* __restrict__ gam, const float* __restrict__ bet,
    const float* __restrict__ mu,  const float* __restrict__ var, int i)
{
    const int m = i / 24, f0 = (i - m * 24) * 4;
    const float* gb = gates + (size_t)m * 384 + f0;
    const f32x4 gi = *(const f32x4*)gb;
    const f32x4 gf = *(const f32x4*)(gb + 96);
    const f32x4 gc = *(const f32x4*)(gb + 192);
    const f32x4 go = *(const f32x4*)(gb + 288);
    float* cp = cst + m * 96 + f0;
    f32x4 cc = *(const f32x4*)cp;
    const f32x4 ga = *(const f32x4*)(gam + f0);
    const f32x4 be = *(const f32x4*)(bet + f0);
    const f32x4 mv = *(const f32x4*)(mu + f0);
    const f32x4 vv = *(const f32x4*)(var + f0);

    u16 hu[4], bu[4];
    f32x4 cn;
#pragma unroll
    for (int j = 0; j < 4; ++j) {
        const float i_ = hsig(gi[j]);
        const float f_ = hsig(gf[j]);
        const float o_ = hsig(go[j]);
        const float c_ = f_ * cc[j] + i_ * tanhf(gc[j]);
        const float h_ = o_ * tanhf(c_);
        cn[j] = c_;
        hu[j] = f2bf(h_);
        const float s = ga[j] * rsqrtf(vv[j] + 1e-3f);
        bu[j] = f2bf((h_ - mv[j]) * s + be[j]);
    }
    *(f32x4*)cp = cn;
    uint2 hp; hp.x = hu[0] | ((unsigned)hu[1] << 16); hp.y = hu[2] | ((unsigned)hu[3] << 16);
    uint2 bp; bp.x = bu[0] | ((unsigned)bu[1] << 16); bp.y = bu[2] | ((unsigned)bu[3] << 16);
    *(uint2*)(hraw + (size_t)m * 96 + f0) = hp;
    *(uint2*)(hbn  + (size_t)m * 96 + f0) = bp;
}

__device__ __forceinline__ void phaseB_body(int t, int gtid,
    const float* gates0, const float* gates1,
    float* c0, float* c1, u16* h0, u16* h1, u16* h0bn, u16* hall,
    const float* g0, const float* be0, const float* mu0, const float* v0,
    const float* g1, const float* be1, const float* mu1, const float* v1)
{
    for (int i = gtid; i < 196608; i += 131072) {
        if (i < 98304) {
            if (t >= 0)
                pw_item(gates1, c1, h1, hall + (size_t)t * 393216,
                        g1, be1, mu1, v1, i);
        } else if (t < 63) {
            pw_item(gates0, c0, h0, h0bn, g0, be0, mu0, v0, i - 98304);
        }
    }
}

// ---------------------------------------------------------------------------
// persistent kernel
// ---------------------------------------------------------------------------
__global__ __launch_bounds__(512, 2) void fused(
    unsigned* bctrs, unsigned* bepoch,
    const u16* xpad, u16* h0, u16* h1, float* c0, float* c1, u16* h0bn,
    float* gates0, float* gates1, u16* hall,
    const u16* Wt0, const u16* Wt1,
    const float* b0, const float* b1,
    const float* g0, const float* be0, const float* mu0, const float* v0,
    const float* g1, const float* be1, const float* mu1, const float* v1)
{
    __shared__ u16 As[2][2][64][40];
    __shared__ u16 Bs[2][2][96][40];
    const int blk = blockIdx.x;
    const int gtid = blk * 512 + threadIdx.x;    // < 131072

    unsigned bar = 0;
    for (int t = -1; t < 64; ++t) {
        conv_pair(t, blk, threadIdx.x, As, Bs, xpad, h0, h1, h0bn,
                  Wt0, Wt1, b0, b1, gates0, gates1);
        gridbar(bctrs, bepoch, ++bar, blk);
        phaseB_body(t, gtid, gates0, gates1, c0, c1, h0, h1, h0bn, hall,
                    g0, be0, mu0, v0, g1, be1, mu1, v1);
        gridbar(bctrs, bepoch, ++bar, blk);
    }
}

// ---------------------------------------------------------------------------
// fallback per-step kernels
// ---------------------------------------------------------------------------
__global__ __launch_bounds__(512, 2) void stepA(int t,
    const u16* xpad, u16* h0, u16* h1, u16* h0bn,
    const u16* Wt0, const u16* Wt1, const float* b0, const float* b1,
    float* gates0, float* gates1)
{
    __shared__ u16 As[2][2][64][40];
    __shared__ u16 Bs[2][2][96][40];
    conv_pair(t, blockIdx.x, threadIdx.x, As, Bs, xpad, h0, h1, h0bn,
              Wt0, Wt1, b0, b1, gates0, gates1);
}

__global__ __launch_bounds__(256) void stepB(int t,
    const float* gates0, const float* gates1,
    float* c0, float* c1, u16* h0, u16* h1, u16* h0bn, u16* hall,
    const float* g0, const float* be0, const float* mu0, const float* v0,
    const float* g1, const float* be1, const float* mu1, const float* v1)
{
    const int gtid = blockIdx.x * 256 + threadIdx.x;   // 512 blocks -> <131072
    phaseB_body(t, gtid, gates0, gates1, c0, c1, h0, h1, h0bn, hall,
                g0, be0, mu0, v0, g1, be1, mu1, v1);
}

// ---------------------------------------------------------------------------
// dense tail (unchanged)
// ---------------------------------------------------------------------------
__global__ void dense_partial(const u16* __restrict__ hall,
                              const float* __restrict__ Wd,
                              float* __restrict__ partial)
{
    const int k0 = blockIdx.x * 2048;
    const int tt = k0 / 24576;
    const int r0 = k0 - tt * 24576;
    const int t  = threadIdx.x;          // 0..159
    const int b  = t / 10;
    const int nc = t - b * 10;
    const u16* hp = hall + (size_t)(tt * 16 + b) * 24576 + r0;
    const float* wp = Wd + (size_t)k0 * 10 + nc;
    float acc = 0.0f;
    for (int j = 0; j < 2048; j += 8) {
        const u16x8 hv = *(const u16x8*)(hp + j);
#pragma unroll
        for (int u = 0; u < 8; ++u)
            acc = fmaf(bf2f(hv[u]), wp[(size_t)(j + u) * 10], acc);
    }
    partial[blockIdx.x * 160 + t] = acc;
}

__global__ void dense_reduce(const float* __restrict__ partial,
                             const float* __restrict__ bd,
                             float* __restrict__ out)
{
    const int t = threadIdx.x;           // 0..159
    const int nc = t - (t / 10) * 10;
    float acc = bd[nc];
    for (int p = 0; p < 768; ++p) acc += partial[p * 160 + t];
    out[t] = acc;
}

// ---------------------------------------------------------------------------
extern "C" void kernel_launch(void* const* d_in, const int* in_sizes, int n_in,
                              void* d_out, int out_size, void* d_ws, size_t ws_size,
                              hipStream_t stream)
{
    const float* x    = (const float*)d_in[0];
    const float* Wx0  = (const float*)d_in[1];
    const float* Wh0  = (const float*)d_in[2];
    const float* b0p  = (const float*)d_in[3];
    const float* g0p  = (const float*)d_in[4];
    const float* be0p = (const float*)d_in[5];
    const float* mu0p = (const float*)d_in[6];
    const float* v0p  = (const float*)d_in[7];
    const float* Wx1  = (const float*)d_in[8];
    const float* Wh1  = (const float*)d_in[9];
    const float* b1p  = (const float*)d_in[10];
    const float* g1p  = (const float*)d_in[11];
    const float* be1p = (const float*)d_in[12];
    const float* mu1p = (const float*)d_in[13];
    const float* v1p  = (const float*)d_in[14];
    const float* Wd   = (const float*)d_in[15];
    const float* bd   = (const float*)d_in[16];
    float* out = (float*)d_out;

    char* base = (char*)d_ws;
    u16*   h0     = (u16*)(base);                      //   786432 B
    u16*   h1     = (u16*)(base + 786432);             //   786432 B
    float* c0     = (float*)(base + 1572864);          //  1572864 B
    float* c1     = (float*)(base + 3145728);          //  1572864 B
    u16*   h0bn   = (u16*)(base + 4718592);            //   786432 B
    float* gates0 = (float*)(base + 5505024);          //  6291456 B
    float* gates1 = (float*)(base + 11796480);         //  6291456 B
    u16*   xpad   = (u16*)(base + 18087936);           //  4194304 B
    u16*   Wt0    = (u16*)(base + 22282240);           //   737280 B
    u16*   Wt1    = (u16*)(base + 23019520);           //  1327104 B
    u16*   hall   = (u16*)(base + 24346624);           // 50331648 B
    float* part   = (float*)(base + 74678272);         //   491520 B
    unsigned* bctrs  = (unsigned*)(base + 75169792);   //    16384 B (64 x 256B)
    unsigned* bepoch = (unsigned*)(base + 75186176);   //      256 B

    hipMemsetAsync(base, 0, 4718592, stream);          // h0,h1,c0,c1,h0bn = 0
    hipMemsetAsync(bctrs, 0, 16640, stream);           // barrier ctrs + epoch

    prep_x <<<1024, 256, 0, stream>>>(x, xpad);
    wtrans0<<<1440, 256, 0, stream>>>(Wx0, Wh0, Wt0);
    wtrans1<<<2592, 256, 0, stream>>>(Wx1, Wh1, Wt1);

    void* args[] = {
        (void*)&bctrs, (void*)&bepoch,
        (void*)&xpad, (void*)&h0, (void*)&h1, (void*)&c0, (void*)&c1,
        (void*)&h0bn, (void*)&gates0, (void*)&gates1, (void*)&hall,
        (void*)&Wt0, (void*)&Wt1, (void*)&b0p, (void*)&b1p,
        (void*)&g0p, (void*)&be0p, (void*)&mu0p, (void*)&v0p,
        (void*)&g1p, (void*)&be1p, (void*)&mu1p, (void*)&v1p
    };
    hipError_t ce = hipLaunchCooperativeKernel((void*)fused, dim3(256),
                                               dim3(512), args, 0, stream);
    if (ce != hipSuccess) {
        (void)hipGetLastError();   // clear sticky error, use fallback path
        for (int t = -1; t < 64; ++t) {
            stepA<<<256, 512, 0, stream>>>(t, xpad, h0, h1, h0bn,
                                           Wt0, Wt1, b0p, b1p, gates0, gates1);
            stepB<<<512, 256, 0, stream>>>(t, gates0, gates1, c0, c1, h0, h1,
                                           h0bn, hall, g0p, be0p, mu0p, v0p,
                                           g1p, be1p, mu1p, v1p);
        }
    }

    dense_partial<<<768, 160, 0, stream>>>(hall, Wd, part);
    dense_reduce <<<1, 160, 0, stream>>>(part, bd, out);
}

// Round 8
// 2581.789 us; speedup vs baseline: 5.5252x; 1.6889x over previous
//
#include <hip/hip_runtime.h>
#include <math.h>

// ImuModel v8: XCD-local persistent ConvLSTM.
// Key idea: the recurrence is batch-separable (3x3 halo never crosses batch
// images). Batch pair {2k,2k+1} -> XCD k. Blocks self-register by physical
// HW_REG_XCC_ID; if every XCD has exactly 32 blocks, each XCD group runs its
// 64-step recurrence independently with cheap XCD-local barriers (same-L2
// write-through visibility + L1-only buffer_inv; no wbl2 / L2 inv / HBM
// refetch). Otherwise: deterministic fallback to v7 global-barrier path.

typedef __attribute__((ext_vector_type(8))) short     bf16x8;
typedef __attribute__((ext_vector_type(8))) unsigned short u16x8;
typedef __attribute__((ext_vector_type(4))) float     f32x4;
typedef unsigned short u16;

__device__ __forceinline__ float hsig(float x) {
    return fminf(fmaxf(0.2f * x + 0.5f, 0.0f), 1.0f);
}
__device__ __forceinline__ float bf2f(u16 u) {
    union { unsigned int i; float f; } v; v.i = ((unsigned int)u) << 16; return v.f;
}
__device__ __forceinline__ u16 f2bf(float f) {
    union { float f; unsigned int i; } v; v.f = f;
    unsigned int r = (v.i + 0x7FFFu + ((v.i >> 16) & 1u)) >> 16;   // RNE
    return (u16)r;
}

// ---------------- global two-level barrier (v7, registration + fallback) ----
__device__ __forceinline__ void gridbar(unsigned* ctrs, unsigned* epoch,
                                        unsigned k, int blk)
{
    __syncthreads();
    if (threadIdx.x == 0) {
        __builtin_amdgcn_fence(__ATOMIC_RELEASE, "agent");
        __hip_atomic_fetch_add(ctrs + (blk & 63) * 64, 1u,
                               __ATOMIC_RELAXED, __HIP_MEMORY_SCOPE_AGENT);
    }
    if (blk == 0 && threadIdx.x < 64) {
        const unsigned target = k * 256u;
        unsigned sum;
        do {
            unsigned v = __hip_atomic_load(ctrs + threadIdx.x * 64,
                                           __ATOMIC_RELAXED,
                                           __HIP_MEMORY_SCOPE_AGENT);
            sum = v;
#pragma unroll
            for (int m = 1; m < 64; m <<= 1)
                sum += __shfl_xor(sum, m, 64);
            if (sum < target) __builtin_amdgcn_s_sleep(2);
        } while (sum < target);
        if (threadIdx.x == 0)
            __hip_atomic_store(epoch, k, __ATOMIC_RELAXED,
                               __HIP_MEMORY_SCOPE_AGENT);
    }
    if (threadIdx.x == 0) {
        while (__hip_atomic_load(epoch, __ATOMIC_RELAXED,
                                 __HIP_MEMORY_SCOPE_AGENT) < k)
            __builtin_amdgcn_s_sleep(4);
        __builtin_amdgcn_fence(__ATOMIC_ACQUIRE, "agent");
    }
    __syncthreads();
}

// ---------------- XCD-local barrier: 32 same-L2 blocks ----------------------
// Visibility within one XCD: vector stores write through L1 to the shared L2
// (drained by the vmcnt(0) the compiler emits before __syncthreads' s_barrier).
// Readers need only a per-CU L1 invalidate. No wbl2, no L2 invalidate.
__device__ __forceinline__ void xbar(unsigned* ctr, unsigned target)
{
    __syncthreads();                  // all block stores are in L2 after this
    if (threadIdx.x == 0) {
        __hip_atomic_fetch_add(ctr, 1u, __ATOMIC_RELAXED,
                               __HIP_MEMORY_SCOPE_AGENT);
        while (__hip_atomic_load(ctr, __ATOMIC_RELAXED,
                                 __HIP_MEMORY_SCOPE_AGENT) < target)
            __builtin_amdgcn_s_sleep(1);
        asm volatile("buffer_inv sc0\n\ts_waitcnt vmcnt(0)" ::: "memory");
    }
    __syncthreads();
}

// ---------------------------------------------------------------------------
// prep kernels (unchanged)
// ---------------------------------------------------------------------------
__global__ __launch_bounds__(256) void prep_x(const float* __restrict__ x,
                                              u16* __restrict__ xpad)
{
    const int idx = blockIdx.x * 256 + threadIdx.x;      // < 262144
    const int t = idx >> 12, b = (idx >> 8) & 15, p = idx & 255;
    const float* src = x + (((size_t)b * 64 + t) * 256 + p) * 6;
    u16x8 v = {};
    v[0] = f2bf(src[0]); v[1] = f2bf(src[1]); v[2] = f2bf(src[2]);
    v[3] = f2bf(src[3]); v[4] = f2bf(src[4]); v[5] = f2bf(src[5]);
    *(u16x8*)(xpad + (size_t)idx * 8) = v;
}

__global__ __launch_bounds__(256) void wtrans0(const float* __restrict__ Wx0,
                                               const float* __restrict__ Wh0,
                                               u16* __restrict__ Wt0)
{
    const int idx = blockIdx.x * 256 + threadIdx.x;      // < 384*960
    const int n = idx / 960, k = idx - n * 960;
    float v = 0.0f;
    if (k < 96) {
        const int q = k >> 3, c = k & 7;
        if (q < 9 && c < 6) v = Wx0[(q * 6 + c) * 384 + n];
    } else {
        v = Wh0[(k - 96) * 384 + n];
    }
    Wt0[idx] = f2bf(v);
}

__global__ __launch_bounds__(256) void wtrans1(const float* __restrict__ Wx1,
                                               const float* __restrict__ Wh1,
                                               u16* __restrict__ Wt1)
{
    const int idx = blockIdx.x * 256 + threadIdx.x;      // < 384*1728
    const int n = idx / 1728, k = idx - n * 1728;
    const float v = (k < 864) ? Wx1[k * 384 + n] : Wh1[(k - 864) * 384 + n];
    Wt1[idx] = f2bf(v);
}

// ---------------------------------------------------------------------------
// paired conv (device): half0 = conv1[t] (KT=1728), half1 = conv0[t+1] (KT=960)
// m0/n0 supplied by caller (group or global tiling). m is GLOBAL row id.
// ---------------------------------------------------------------------------
__device__ void conv_pair(int t, int m0, int n0, int tidx,
    u16 (&As)[2][2][64][40], u16 (&Bs)[2][2][96][40],
    const u16* __restrict__ xpad, const u16* __restrict__ h0,
    const u16* __restrict__ h1,   const u16* __restrict__ h0bn,
    const u16* __restrict__ Wt0,  const u16* __restrict__ Wt1,
    const float* __restrict__ b0, const float* __restrict__ b1,
    float* __restrict__ gates0,   float* __restrict__ gates1)
{
    const int half = tidx >> 8;           // 0: conv1[t], 1: conv0[t+1]
    const int htid = tidx & 255;
    const bool active = half ? (t < 63) : (t >= 0);

    const int lane = htid & 63;
    const int hw   = htid >> 6;
    const int wm = hw >> 1, wn = hw & 1;
    const int fr = lane & 15, fg = lane >> 4;
    const int arow = htid >> 2, seg = htid & 3;
    const int mg = m0 + arow;
    const int py = (mg >> 4) & 15, px = mg & 15, pb = mg >> 8;

    const int   KT   = half ? 960 : 1728;
    const int   NS0  = half ? 3   : 27;
    const int   MYST = half ? 30  : 54;
    const u16*  Wt   = half ? Wt0 : Wt1;
    const u16*  in1  = half ? h0  : h1;
    const u16*  in0  = half ? (xpad + (size_t)(t + 1) * 32768) : h0bn;
    const float* bias = half ? b0 : b1;
    float*      gout = half ? gates0 : gates1;

    f32x4 acc[2][3];
#pragma unroll
    for (int i = 0; i < 2; ++i)
#pragma unroll
        for (int j = 0; j < 3; ++j) acc[i][j] = (f32x4){0.f, 0.f, 0.f, 0.f};

    u16x8 va, vb0, vb1;
    auto stage = [&](int ks) {
        u16x8 z = {};
        va = z;
        if (half && ks < 3) {
            const int q = ks * 4 + seg;           // 12 taps, q<9 real
            const int qd = q / 3;
            const int yy = py + qd - 1;
            const int xx = px + (q - 3 * qd) - 1;
            if (q < 9 && (unsigned)yy < 16u && (unsigned)xx < 16u)
                va = *(const u16x8*)(in0 + (size_t)((pb << 8) + yy * 16 + xx) * 8);
        } else {
            const int s = (ks < NS0) ? ks : ks - NS0;
            const u16* src = (ks < NS0) ? in0 : in1;
            const int q = s / 3;
            const int c0v = (s - 3 * q) * 32 + seg * 8;
            const int qd = q / 3;
            const int yy = py + qd - 1;
            const int xx = px + (q - 3 * qd) - 1;
            if ((unsigned)yy < 16u && (unsigned)xx < 16u)
                va = *(const u16x8*)(src + (size_t)((pb << 8) + yy * 16 + xx) * 96 + c0v);
        }
        const int koff = ks * 32 + seg * 8;
        vb0 = *(const u16x8*)(Wt + (size_t)(n0 + arow) * KT + koff);
        vb1 = z;
        if (htid < 128)
            vb1 = *(const u16x8*)(Wt + (size_t)(n0 + 64 + arow) * KT + koff);
    };
    auto ldsw = [&](int buf) {
        *(u16x8*)(&As[half][buf][arow][seg * 8]) = va;
        *(u16x8*)(&Bs[half][buf][arow][seg * 8]) = vb0;
        if (htid < 128) *(u16x8*)(&Bs[half][buf][64 + arow][seg * 8]) = vb1;
    };

    if (active) { stage(0); ldsw(0); }
    __syncthreads();

    for (int ks = 0; ks < 54; ++ks) {
        const int cur = ks & 1;
        if (active && ks < MYST) {
            if (ks + 1 < MYST) stage(ks + 1);

            bf16x8 af[2], bq[3];
#pragma unroll
            for (int mf = 0; mf < 2; ++mf)
                af[mf] = *(const bf16x8*)(&As[half][cur][wm * 32 + mf * 16 + fr][fg * 8]);
#pragma unroll
            for (int nf = 0; nf < 3; ++nf)
                bq[nf] = *(const bf16x8*)(&Bs[half][cur][wn * 48 + nf * 16 + fr][fg * 8]);

            __builtin_amdgcn_s_setprio(1);
#pragma unroll
            for (int mf = 0; mf < 2; ++mf)
#pragma unroll
                for (int nf = 0; nf < 3; ++nf)
                    acc[mf][nf] = __builtin_amdgcn_mfma_f32_16x16x32_bf16(
                        af[mf], bq[nf], acc[mf][nf], 0, 0, 0);
            __builtin_amdgcn_s_setprio(0);

            if (ks + 1 < MYST) ldsw(cur ^ 1);
        }
        __syncthreads();   // common site for both halves
    }

    if (active) {
#pragma unroll
        for (int nf = 0; nf < 3; ++nf) {
            const int n = n0 + wn * 48 + nf * 16 + fr;
            const float bi = bias[n];
#pragma unroll
            for (int mf = 0; mf < 2; ++mf) {
                const int mrow = m0 + wm * 32 + mf * 16 + fg * 4;
#pragma unroll
                for (int r = 0; r < 4; ++r)
                    gout[(size_t)(mrow + r) * 384 + n] = acc[mf][nf][r] + bi;
            }
        }
    }
}

// ---------------------------------------------------------------------------
// pointwise (by explicit m, f0)
// ---------------------------------------------------------------------------
__device__ __forceinline__ void pw_item(
    const float* __restrict__ gates, float* __restrict__ cst,
    u16* __restrict__ hraw, u16* __restrict__ hbn,
    const float* __restrict__ gam, const float* __restrict__ bet,
    const float* __restrict__ mu,  const float* __restrict__ var,
    int m, int f0)
{
    const float* gb = gates + (size_t)m * 384 + f0;
    const f32x4 gi = *(const f32x4*)gb;
    const f32x4 gf = *(const f32x4*)(gb + 96);
    const f32x4 gc = *(const f32x4*)(gb + 192);
    const f32x4 go = *(const f32x4*)(gb + 288);
    float* cp = cst + m * 96 + f0;
    f32x4 cc = *(const f32x4*)cp;
    const f32x4 ga = *(const f32x4*)(gam + f0);
    const f32x4 be = *(const f32x4*)(bet + f0);
    const f32x4 mv = *(const f32x4*)(mu + f0);
    const f32x4 vv = *(const f32x4*)(var + f0);

    u16 hu[4], bu[4];
    f32x4 cn;
#pragma unroll
    for (int j = 0; j < 4; ++j) {
        const float i_ = hsig(gi[j]);
        const float f_ = hsig(gf[j]);
        const float o_ = hsig(go[j]);
        const float c_ = f_ * cc[j] + i_ * tanhf(gc[j]);
        const float h_ = o_ * tanhf(c_);
        cn[j] = c_;
        hu[j] = f2bf(h_);
        const float s = ga[j] * rsqrtf(vv[j] + 1e-3f);
        bu[j] = f2bf((h_ - mv[j]) * s + be[j]);
    }
    *(f32x4*)cp = cn;
    uint2 hp; hp.x = hu[0] | ((unsigned)hu[1] << 16); hp.y = hu[2] | ((unsigned)hu[3] << 16);
    uint2 bp; bp.x = bu[0] | ((unsigned)bu[1] << 16); bp.y = bu[2] | ((unsigned)bu[3] << 16);
    *(uint2*)(hraw + (size_t)m * 96 + f0) = hp;
    *(uint2*)(hbn  + (size_t)m * 96 + f0) = bp;
}

// fallback (device-wide) pw phase: items over all 4096 rows
__device__ __forceinline__ void phaseB_body(int t, int gtid,
    const float* gates0, const float* gates1,
    float* c0, float* c1, u16* h0, u16* h1, u16* h0bn, u16* hall,
    const float* g0, const float* be0, const float* mu0, const float* v0,
    const float* g1, const float* be1, const float* mu1, const float* v1)
{
    for (int i = gtid; i < 196608; i += 131072) {
        if (i < 98304) {
            if (t >= 0) {
                const int m = i / 24, f0 = (i - m * 24) * 4;
                pw_item(gates1, c1, h1, hall + (size_t)t * 393216,
                        g1, be1, mu1, v1, m, f0);
            }
        } else if (t < 63) {
            const int j = i - 98304;
            const int m = j / 24, f0 = (j - m * 24) * 4;
            pw_item(gates0, c0, h0, h0bn, g0, be0, mu0, v0, m, f0);
        }
    }
}

// group-local pw phase: 512 rows of this XCD's batch pair, 16384 threads
__device__ __forceinline__ void phaseB_group(int t, int grp, int gid,
    const float* gates0, const float* gates1,
    float* c0, float* c1, u16* h0, u16* h1, u16* h0bn, u16* hall,
    const float* g0, const float* be0, const float* mu0, const float* v0,
    const float* g1, const float* be1, const float* mu1, const float* v1)
{
    for (int i = gid; i < 24576; i += 16384) {
        const bool l1 = (i < 12288);
        const int j = l1 ? i : i - 12288;
        const int r = j / 24;
        const int f0 = (j - r * 24) * 4;
        const int m = grp * 512 + r;
        if (l1) {
            if (t >= 0)
                pw_item(gates1, c1, h1, hall + (size_t)t * 393216,
                        g1, be1, mu1, v1, m, f0);
        } else if (t < 63) {
            pw_item(gates0, c0, h0, h0bn, g0, be0, mu0, v0, m, f0);
        }
    }
}

// ---------------------------------------------------------------------------
// persistent kernel: XCD-grouped if placement allows, else global barriers
// ---------------------------------------------------------------------------
__global__ __launch_bounds__(512, 2) void fused(
    unsigned* bctrs, unsigned* bepoch, unsigned* reg8, unsigned* xctrs,
    const u16* xpad, u16* h0, u16* h1, float* c0, float* c1, u16* h0bn,
    float* gates0, float* gates1, u16* hall,
    const u16* Wt0, const u16* Wt1,
    const float* b0, const float* b1,
    const float* g0, const float* be0, const float* mu0, const float* v0,
    const float* g1, const float* be1, const float* mu1, const float* v1)
{
    __shared__ u16 As[2][2][64][40];
    __shared__ u16 Bs[2][2][96][40];
    __shared__ unsigned shinfo[3];      // xcc, slot, ok
    const int blk = blockIdx.x;

    // --- register this block with its physical XCD ---
    if (threadIdx.x == 0) {
        unsigned xcc;
        asm volatile("s_getreg_b32 %0, hwreg(HW_REG_XCC_ID)" : "=s"(xcc));
        xcc &= 7u;
        unsigned slot = __hip_atomic_fetch_add(reg8 + xcc * 64, 1u,
                                               __ATOMIC_RELAXED,
                                               __HIP_MEMORY_SCOPE_AGENT);
        shinfo[0] = xcc; shinfo[1] = slot;
    }
    gridbar(bctrs, bepoch, 1, blk);     // registration settled device-wide
    if (threadIdx.x == 0) {
        unsigned ok = 1;
#pragma unroll
        for (int k = 0; k < 8; ++k)
            ok &= (__hip_atomic_load(reg8 + k * 64, __ATOMIC_RELAXED,
                                     __HIP_MEMORY_SCOPE_AGENT) == 32u);
        shinfo[2] = ok;
    }
    __syncthreads();
    const unsigned grp  = shinfo[0];
    const unsigned slot = shinfo[1];
    const bool grouped  = (shinfo[2] != 0u);

    if (grouped) {
        // XCD k owns batches {2k,2k+1}: global rows [512k, 512k+512).
        // slot 0..31 -> m-tile (slot>>2) within group, n-tile (slot&3).
        const int m0 = (int)grp * 512 + (int)(slot >> 2) * 64;
        const int n0 = (int)(slot & 3) * 96;
        const int gid = (int)slot * 512 + threadIdx.x;
        unsigned* gc = xctrs + grp * 64;
        unsigned bar = 0;
        for (int t = -1; t < 64; ++t) {
            conv_pair(t, m0, n0, threadIdx.x, As, Bs, xpad, h0, h1, h0bn,
                      Wt0, Wt1, b0, b1, gates0, gates1);
            xbar(gc, (++bar) * 32u);
            phaseB_group(t, (int)grp, gid, gates0, gates1, c0, c1, h0, h1,
                         h0bn, hall, g0, be0, mu0, v0, g1, be1, mu1, v1);
            xbar(gc, (++bar) * 32u);
        }
    } else {
        const int m0 = (blk >> 2) * 64;
        const int n0 = (blk & 3) * 96;
        const int gtid = blk * 512 + threadIdx.x;
        unsigned bar = 1;                   // epoch 1 used by registration
        for (int t = -1; t < 64; ++t) {
            conv_pair(t, m0, n0, threadIdx.x, As, Bs, xpad, h0, h1, h0bn,
                      Wt0, Wt1, b0, b1, gates0, gates1);
            gridbar(bctrs, bepoch, ++bar, blk);
            phaseB_body(t, gtid, gates0, gates1, c0, c1, h0, h1, h0bn, hall,
                        g0, be0, mu0, v0, g1, be1, mu1, v1);
            gridbar(bctrs, bepoch, ++bar, blk);
        }
    }
}

// ---------------------------------------------------------------------------
// fallback per-step kernels (used only if cooperative launch itself fails)
// ---------------------------------------------------------------------------
__global__ __launch_bounds__(512, 2) void stepA(int t,
    const u16* xpad, u16* h0, u16* h1, u16* h0bn,
    const u16* Wt0, const u16* Wt1, const float* b0, const float* b1,
    float* gates0, float* gates1)
{
    __shared__ u16 As[2][2][64][40];
    __shared__ u16 Bs[2][2][96][40];
    conv_pair(t, (blockIdx.x >> 2) * 64, (blockIdx.x & 3) * 96, threadIdx.x,
              As, Bs, xpad, h0, h1, h0bn, Wt0, Wt1, b0, b1, gates0, gates1);
}

__global__ __launch_bounds__(256) void stepB(int t,
    const float* gates0, const float* gates1,
    float* c0, float* c1, u16* h0, u16* h1, u16* h0bn, u16* hall,
    const float* g0, const float* be0, const float* mu0, const float* v0,
    const float* g1, const float* be1, const float* mu1, const float* v1)
{
    const int gtid = blockIdx.x * 256 + threadIdx.x;   // 512 blocks -> <131072
    phaseB_body(t, gtid, gates0, gates1, c0, c1, h0, h1, h0bn, hall,
                g0, be0, mu0, v0, g1, be1, mu1, v1);
}

// ---------------------------------------------------------------------------
// dense tail (unchanged)
// ---------------------------------------------------------------------------
__global__ void dense_partial(const u16* __restrict__ hall,
                              const float* __restrict__ Wd,
                              float* __restrict__ partial)
{
    const int k0 = blockIdx.x * 2048;
    const int tt = k0 / 24576;
    const int r0 = k0 - tt * 24576;
    const int t  = threadIdx.x;          // 0..159
    const int b  = t / 10;
    const int nc = t - b * 10;
    const u16* hp = hall + (size_t)(tt * 16 + b) * 24576 + r0;
    const float* wp = Wd + (size_t)k0 * 10 + nc;
    float acc = 0.0f;
    for (int j = 0; j < 2048; j += 8) {
        const u16x8 hv = *(const u16x8*)(hp + j);
#pragma unroll
        for (int u = 0; u < 8; ++u)
            acc = fmaf(bf2f(hv[u]), wp[(size_t)(j + u) * 10], acc);
    }
    partial[blockIdx.x * 160 + t] = acc;
}

__global__ void dense_reduce(const float* __restrict__ partial,
                             const float* __restrict__ bd,
                             float* __restrict__ out)
{
    const int t = threadIdx.x;           // 0..159
    const int nc = t - (t / 10) * 10;
    float acc = bd[nc];
    for (int p = 0; p < 768; ++p) acc += partial[p * 160 + t];
    out[t] = acc;
}

// ---------------------------------------------------------------------------
extern "C" void kernel_launch(void* const* d_in, const int* in_sizes, int n_in,
                              void* d_out, int out_size, void* d_ws, size_t ws_size,
                              hipStream_t stream)
{
    const float* x    = (const float*)d_in[0];
    const float* Wx0  = (const float*)d_in[1];
    const float* Wh0  = (const float*)d_in[2];
    const float* b0p  = (const float*)d_in[3];
    const float* g0p  = (const float*)d_in[4];
    const float* be0p = (const float*)d_in[5];
    const float* mu0p = (const float*)d_in[6];
    const float* v0p  = (const float*)d_in[7];
    const float* Wx1  = (const float*)d_in[8];
    const float* Wh1  = (const float*)d_in[9];
    const float* b1p  = (const float*)d_in[10];
    const float* g1p  = (const float*)d_in[11];
    const float* be1p = (const float*)d_in[12];
    const float* mu1p = (const float*)d_in[13];
    const float* v1p  = (const float*)d_in[14];
    const float* Wd   = (const float*)d_in[15];
    const float* bd   = (const float*)d_in[16];
    float* out = (float*)d_out;

    char* base = (char*)d_ws;
    u16*   h0     = (u16*)(base);                      //   786432 B
    u16*   h1     = (u16*)(base + 786432);             //   786432 B
    float* c0     = (float*)(base + 1572864);          //  1572864 B
    float* c1     = (float*)(base + 3145728);          //  1572864 B
    u16*   h0bn   = (u16*)(base + 4718592);            //   786432 B
    float* gates0 = (float*)(base + 5505024);          //  6291456 B
    float* gates1 = (float*)(base + 11796480);         //  6291456 B
    u16*   xpad   = (u16*)(base + 18087936);           //  4194304 B
    u16*   Wt0    = (u16*)(base + 22282240);           //   737280 B
    u16*   Wt1    = (u16*)(base + 23019520);           //  1327104 B
    u16*   hall   = (u16*)(base + 24346624);           // 50331648 B
    float* part   = (float*)(base + 74678272);         //   491520 B
    unsigned* bctrs  = (unsigned*)(base + 75169792);   //  16384 B (64 x 256B)
    unsigned* bepoch = (unsigned*)(base + 75186176);   //    256 B
    unsigned* reg8   = (unsigned*)(base + 75186432);   //   2048 B (8 x 256B)
    unsigned* xctrs  = (unsigned*)(base + 75188480);   //   2048 B (8 x 256B)

    hipMemsetAsync(base, 0, 4718592, stream);          // h0,h1,c0,c1,h0bn = 0
    hipMemsetAsync(bctrs, 0, 20736, stream);           // all barrier state = 0

    prep_x <<<1024, 256, 0, stream>>>(x, xpad);
    wtrans0<<<1440, 256, 0, stream>>>(Wx0, Wh0, Wt0);
    wtrans1<<<2592, 256, 0, stream>>>(Wx1, Wh1, Wt1);

    void* args[] = {
        (void*)&bctrs, (void*)&bepoch, (void*)&reg8, (void*)&xctrs,
        (void*)&xpad, (void*)&h0, (void*)&h1, (void*)&c0, (void*)&c1,
        (void*)&h0bn, (void*)&gates0, (void*)&gates1, (void*)&hall,
        (void*)&Wt0, (void*)&Wt1, (void*)&b0p, (void*)&b1p,
        (void*)&g0p, (void*)&be0p, (void*)&mu0p, (void*)&v0p,
        (void*)&g1p, (void*)&be1p, (void*)&mu1p, (void*)&v1p
    };
    hipError_t ce = hipLaunchCooperativeKernel((void*)fused, dim3(256),
                                               dim3(512), args, 0, stream);
    if (ce != hipSuccess) {
        (void)hipGetLastError();   // clear sticky error, use fallback path
        for (int t = -1; t < 64; ++t) {
            stepA<<<256, 512, 0, stream>>>(t, xpad, h0, h1, h0bn,
                                           Wt0, Wt1, b0p, b1p, gates0, gates1);
            stepB<<<512, 256, 0, stream>>>(t, gates0, gates1, c0, c1, h0, h1,
                                           h0bn, hall, g0p, be0p, mu0p, v0p,
                                           g1p, be1p, mu1p, v1p);
        }
    }

    dense_partial<<<768, 160, 0, stream>>>(hall, Wd, part);
    dense_reduce <<<1, 160, 0, stream>>>(part, bd, out);
}

// Round 9
// 2476.229 us; speedup vs baseline: 5.7607x; 1.0426x over previous
//
#include <hip/hip_runtime.h>
#include <math.h>

// ImuModel v9: XCD-local persistent ConvLSTM, contention-free XCD barrier.
// v8's xbar (single counter/XCD) measured ~11us: 32 RMWs serialized on one
// line while 32 spinners steal it. v9: every block has its own 128B-spaced
// slot (parallel arrivals), every leader self-detects via 32-lane gather +
// shfl-reduce (no epoch hop, no shared spin line). L1 buffer_inv on exit
// unchanged from v8 (proven). Everything else identical to v8.

typedef __attribute__((ext_vector_type(8))) short     bf16x8;
typedef __attribute__((ext_vector_type(8))) unsigned short u16x8;
typedef __attribute__((ext_vector_type(4))) float     f32x4;
typedef unsigned short u16;

__device__ __forceinline__ float hsig(float x) {
    return fminf(fmaxf(0.2f * x + 0.5f, 0.0f), 1.0f);
}
__device__ __forceinline__ float bf2f(u16 u) {
    union { unsigned int i; float f; } v; v.i = ((unsigned int)u) << 16; return v.f;
}
__device__ __forceinline__ u16 f2bf(float f) {
    union { float f; unsigned int i; } v; v.f = f;
    unsigned int r = (v.i + 0x7FFFu + ((v.i >> 16) & 1u)) >> 16;   // RNE
    return (u16)r;
}

// ---------------- global two-level barrier (registration + fallback) --------
__device__ __forceinline__ void gridbar(unsigned* ctrs, unsigned* epoch,
                                        unsigned k, int blk)
{
    __syncthreads();
    if (threadIdx.x == 0) {
        __builtin_amdgcn_fence(__ATOMIC_RELEASE, "agent");
        __hip_atomic_fetch_add(ctrs + (blk & 63) * 64, 1u,
                               __ATOMIC_RELAXED, __HIP_MEMORY_SCOPE_AGENT);
    }
    if (blk == 0 && threadIdx.x < 64) {
        const unsigned target = k * 256u;
        unsigned sum;
        do {
            unsigned v = __hip_atomic_load(ctrs + threadIdx.x * 64,
                                           __ATOMIC_RELAXED,
                                           __HIP_MEMORY_SCOPE_AGENT);
            sum = v;
#pragma unroll
            for (int m = 1; m < 64; m <<= 1)
                sum += __shfl_xor(sum, m, 64);
            if (sum < target) __builtin_amdgcn_s_sleep(2);
        } while (sum < target);
        if (threadIdx.x == 0)
            __hip_atomic_store(epoch, k, __ATOMIC_RELAXED,
                               __HIP_MEMORY_SCOPE_AGENT);
    }
    if (threadIdx.x == 0) {
        while (__hip_atomic_load(epoch, __ATOMIC_RELAXED,
                                 __HIP_MEMORY_SCOPE_AGENT) < k)
            __builtin_amdgcn_s_sleep(4);
        __builtin_amdgcn_fence(__ATOMIC_ACQUIRE, "agent");
    }
    __syncthreads();
}

// ---------------- XCD-local barrier v9: 32 slots, all-leader self-detect ----
// slots: this XCD's 32 slots, 32 u32 (128B) apart. myslot: this block's slot.
// target = k*32 (monotonic). Same-L2 visibility: stores drained to L2 by the
// vmcnt(0) before __syncthreads' s_barrier; readers invalidate L1 only.
__device__ __forceinline__ void xbar(unsigned* slots, int myslot,
                                     unsigned target)
{
    __syncthreads();                  // all block stores are in L2 after this
    if (threadIdx.x == 0)
        __hip_atomic_fetch_add(slots + myslot * 32, 1u,
                               __ATOMIC_RELAXED, __HIP_MEMORY_SCOPE_AGENT);
    if (threadIdx.x < 32) {
        unsigned sum;
        do {
            unsigned v = __hip_atomic_load(slots + threadIdx.x * 32,
                                           __ATOMIC_RELAXED,
                                           __HIP_MEMORY_SCOPE_AGENT);
            sum = v;
#pragma unroll
            for (int m = 1; m < 32; m <<= 1)
                sum += __shfl_xor(sum, m, 64);
            if (sum < target) __builtin_amdgcn_s_sleep(2);
        } while (sum < target);
        asm volatile("buffer_inv sc0\n\ts_waitcnt vmcnt(0)" ::: "memory");
    }
    __syncthreads();
}

// ---------------------------------------------------------------------------
// prep kernels (unchanged)
// ---------------------------------------------------------------------------
__global__ __launch_bounds__(256) void prep_x(const float* __restrict__ x,
                                              u16* __restrict__ xpad)
{
    const int idx = blockIdx.x * 256 + threadIdx.x;      // < 262144
    const int t = idx >> 12, b = (idx >> 8) & 15, p = idx & 255;
    const float* src = x + (((size_t)b * 64 + t) * 256 + p) * 6;
    u16x8 v = {};
    v[0] = f2bf(src[0]); v[1] = f2bf(src[1]); v[2] = f2bf(src[2]);
    v[3] = f2bf(src[3]); v[4] = f2bf(src[4]); v[5] = f2bf(src[5]);
    *(u16x8*)(xpad + (size_t)idx * 8) = v;
}

__global__ __launch_bounds__(256) void wtrans0(const float* __restrict__ Wx0,
                                               const float* __restrict__ Wh0,
                                               u16* __restrict__ Wt0)
{
    const int idx = blockIdx.x * 256 + threadIdx.x;      // < 384*960
    const int n = idx / 960, k = idx - n * 960;
    float v = 0.0f;
    if (k < 96) {
        const int q = k >> 3, c = k & 7;
        if (q < 9 && c < 6) v = Wx0[(q * 6 + c) * 384 + n];
    } else {
        v = Wh0[(k - 96) * 384 + n];
    }
    Wt0[idx] = f2bf(v);
}

__global__ __launch_bounds__(256) void wtrans1(const float* __restrict__ Wx1,
                                               const float* __restrict__ Wh1,
                                               u16* __restrict__ Wt1)
{
    const int idx = blockIdx.x * 256 + threadIdx.x;      // < 384*1728
    const int n = idx / 1728, k = idx - n * 1728;
    const float v = (k < 864) ? Wx1[k * 384 + n] : Wh1[(k - 864) * 384 + n];
    Wt1[idx] = f2bf(v);
}

// ---------------------------------------------------------------------------
// paired conv (device): half0 = conv1[t] (KT=1728), half1 = conv0[t+1] (KT=960)
// ---------------------------------------------------------------------------
__device__ void conv_pair(int t, int m0, int n0, int tidx,
    u16 (&As)[2][2][64][40], u16 (&Bs)[2][2][96][40],
    const u16* __restrict__ xpad, const u16* __restrict__ h0,
    const u16* __restrict__ h1,   const u16* __restrict__ h0bn,
    const u16* __restrict__ Wt0,  const u16* __restrict__ Wt1,
    const float* __restrict__ b0, const float* __restrict__ b1,
    float* __restrict__ gates0,   float* __restrict__ gates1)
{
    const int half = tidx >> 8;           // 0: conv1[t], 1: conv0[t+1]
    const int htid = tidx & 255;
    const bool active = half ? (t < 63) : (t >= 0);

    const int lane = htid & 63;
    const int hw   = htid >> 6;
    const int wm = hw >> 1, wn = hw & 1;
    const int fr = lane & 15, fg = lane >> 4;
    const int arow = htid >> 2, seg = htid & 3;
    const int mg = m0 + arow;
    const int py = (mg >> 4) & 15, px = mg & 15, pb = mg >> 8;

    const int   KT   = half ? 960 : 1728;
    const int   NS0  = half ? 3   : 27;
    const int   MYST = half ? 30  : 54;
    const u16*  Wt   = half ? Wt0 : Wt1;
    const u16*  in1  = half ? h0  : h1;
    const u16*  in0  = half ? (xpad + (size_t)(t + 1) * 32768) : h0bn;
    const float* bias = half ? b0 : b1;
    float*      gout = half ? gates0 : gates1;

    f32x4 acc[2][3];
#pragma unroll
    for (int i = 0; i < 2; ++i)
#pragma unroll
        for (int j = 0; j < 3; ++j) acc[i][j] = (f32x4){0.f, 0.f, 0.f, 0.f};

    u16x8 va, vb0, vb1;
    auto stage = [&](int ks) {
        u16x8 z = {};
        va = z;
        if (half && ks < 3) {
            const int q = ks * 4 + seg;           // 12 taps, q<9 real
            const int qd = q / 3;
            const int yy = py + qd - 1;
            const int xx = px + (q - 3 * qd) - 1;
            if (q < 9 && (unsigned)yy < 16u && (unsigned)xx < 16u)
                va = *(const u16x8*)(in0 + (size_t)((pb << 8) + yy * 16 + xx) * 8);
        } else {
            const int s = (ks < NS0) ? ks : ks - NS0;
            const u16* src = (ks < NS0) ? in0 : in1;
            const int q = s / 3;
            const int c0v = (s - 3 * q) * 32 + seg * 8;
            const int qd = q / 3;
            const int yy = py + qd - 1;
            const int xx = px + (q - 3 * qd) - 1;
            if ((unsigned)yy < 16u && (unsigned)xx < 16u)
                va = *(const u16x8*)(src + (size_t)((pb << 8) + yy * 16 + xx) * 96 + c0v);
        }
        const int koff = ks * 32 + seg * 8;
        vb0 = *(const u16x8*)(Wt + (size_t)(n0 + arow) * KT + koff);
        vb1 = z;
        if (htid < 128)
            vb1 = *(const u16x8*)(Wt + (size_t)(n0 + 64 + arow) * KT + koff);
    };
    auto ldsw = [&](int buf) {
        *(u16x8*)(&As[half][buf][arow][seg * 8]) = va;
        *(u16x8*)(&Bs[half][buf][arow][seg * 8]) = vb0;
        if (htid < 128) *(u16x8*)(&Bs[half][buf][64 + arow][seg * 8]) = vb1;
    };

    if (active) { stage(0); ldsw(0); }
    __syncthreads();

    for (int ks = 0; ks < 54; ++ks) {
        const int cur = ks & 1;
        if (active && ks < MYST) {
            if (ks + 1 < MYST) stage(ks + 1);

            bf16x8 af[2], bq[3];
#pragma unroll
            for (int mf = 0; mf < 2; ++mf)
                af[mf] = *(const bf16x8*)(&As[half][cur][wm * 32 + mf * 16 + fr][fg * 8]);
#pragma unroll
            for (int nf = 0; nf < 3; ++nf)
                bq[nf] = *(const bf16x8*)(&Bs[half][cur][wn * 48 + nf * 16 + fr][fg * 8]);

            __builtin_amdgcn_s_setprio(1);
#pragma unroll
            for (int mf = 0; mf < 2; ++mf)
#pragma unroll
                for (int nf = 0; nf < 3; ++nf)
                    acc[mf][nf] = __builtin_amdgcn_mfma_f32_16x16x32_bf16(
                        af[mf], bq[nf], acc[mf][nf], 0, 0, 0);
            __builtin_amdgcn_s_setprio(0);

            if (ks + 1 < MYST) ldsw(cur ^ 1);
        }
        __syncthreads();   // common site for both halves
    }

    if (active) {
#pragma unroll
        for (int nf = 0; nf < 3; ++nf) {
            const int n = n0 + wn * 48 + nf * 16 + fr;
            const float bi = bias[n];
#pragma unroll
            for (int mf = 0; mf < 2; ++mf) {
                const int mrow = m0 + wm * 32 + mf * 16 + fg * 4;
#pragma unroll
                for (int r = 0; r < 4; ++r)
                    gout[(size_t)(mrow + r) * 384 + n] = acc[mf][nf][r] + bi;
            }
        }
    }
}

// ---------------------------------------------------------------------------
// pointwise (by explicit m, f0)
// ---------------------------------------------------------------------------
__device__ __forceinline__ void pw_item(
    const float* __restrict__ gates, float* __restrict__ cst,
    u16* __restrict__ hraw, u16* __restrict__ hbn,
    const float* __restrict__ gam, const float* __restrict__ bet,
    const float* __restrict__ mu,  const float* __restrict__ var,
    int m, int f0)
{
    const float* gb = gates + (size_t)m * 384 + f0;
    const f32x4 gi = *(const f32x4*)gb;
    const f32x4 gf = *(const f32x4*)(gb + 96);
    const f32x4 gc = *(const f32x4*)(gb + 192);
    const f32x4 go = *(const f32x4*)(gb + 288);
    float* cp = cst + m * 96 + f0;
    f32x4 cc = *(const f32x4*)cp;
    const f32x4 ga = *(const f32x4*)(gam + f0);
    const f32x4 be = *(const f32x4*)(bet + f0);
    const f32x4 mv = *(const f32x4*)(mu + f0);
    const f32x4 vv = *(const f32x4*)(var + f0);

    u16 hu[4], bu[4];
    f32x4 cn;
#pragma unroll
    for (int j = 0; j < 4; ++j) {
        const float i_ = hsig(gi[j]);
        const float f_ = hsig(gf[j]);
        const float o_ = hsig(go[j]);
        const float c_ = f_ * cc[j] + i_ * tanhf(gc[j]);
        const float h_ = o_ * tanhf(c_);
        cn[j] = c_;
        hu[j] = f2bf(h_);
        const float s = ga[j] * rsqrtf(vv[j] + 1e-3f);
        bu[j] = f2bf((h_ - mv[j]) * s + be[j]);
    }
    *(f32x4*)cp = cn;
    uint2 hp; hp.x = hu[0] | ((unsigned)hu[1] << 16); hp.y = hu[2] | ((unsigned)hu[3] << 16);
    uint2 bp; bp.x = bu[0] | ((unsigned)bu[1] << 16); bp.y = bu[2] | ((unsigned)bu[3] << 16);
    *(uint2*)(hraw + (size_t)m * 96 + f0) = hp;
    *(uint2*)(hbn  + (size_t)m * 96 + f0) = bp;
}

// fallback (device-wide) pw phase
__device__ __forceinline__ void phaseB_body(int t, int gtid,
    const float* gates0, const float* gates1,
    float* c0, float* c1, u16* h0, u16* h1, u16* h0bn, u16* hall,
    const float* g0, const float* be0, const float* mu0, const float* v0,
    const float* g1, const float* be1, const float* mu1, const float* v1)
{
    for (int i = gtid; i < 196608; i += 131072) {
        if (i < 98304) {
            if (t >= 0) {
                const int m = i / 24, f0 = (i - m * 24) * 4;
                pw_item(gates1, c1, h1, hall + (size_t)t * 393216,
                        g1, be1, mu1, v1, m, f0);
            }
        } else if (t < 63) {
            const int j = i - 98304;
            const int m = j / 24, f0 = (j - m * 24) * 4;
            pw_item(gates0, c0, h0, h0bn, g0, be0, mu0, v0, m, f0);
        }
    }
}

// group-local pw phase: 512 rows of this XCD's batch pair, 16384 threads
__device__ __forceinline__ void phaseB_group(int t, int grp, int gid,
    const float* gates0, const float* gates1,
    float* c0, float* c1, u16* h0, u16* h1, u16* h0bn, u16* hall,
    const float* g0, const float* be0, const float* mu0, const float* v0,
    const float* g1, const float* be1, const float* mu1, const float* v1)
{
    for (int i = gid; i < 24576; i += 16384) {
        const bool l1 = (i < 12288);
        const int j = l1 ? i : i - 12288;
        const int r = j / 24;
        const int f0 = (j - r * 24) * 4;
        const int m = grp * 512 + r;
        if (l1) {
            if (t >= 0)
                pw_item(gates1, c1, h1, hall + (size_t)t * 393216,
                        g1, be1, mu1, v1, m, f0);
        } else if (t < 63) {
            pw_item(gates0, c0, h0, h0bn, g0, be0, mu0, v0, m, f0);
        }
    }
}

// ---------------------------------------------------------------------------
// persistent kernel: XCD-grouped if placement allows, else global barriers
// ---------------------------------------------------------------------------
__global__ __launch_bounds__(512, 2) void fused(
    unsigned* bctrs, unsigned* bepoch, unsigned* reg8, unsigned* xslots,
    const u16* xpad, u16* h0, u16* h1, float* c0, float* c1, u16* h0bn,
    float* gates0, float* gates1, u16* hall,
    const u16* Wt0, const u16* Wt1,
    const float* b0, const float* b1,
    const float* g0, const float* be0, const float* mu0, const float* v0,
    const float* g1, const float* be1, const float* mu1, const float* v1)
{
    __shared__ u16 As[2][2][64][40];
    __shared__ u16 Bs[2][2][96][40];
    __shared__ unsigned shinfo[3];      // xcc, slot, ok
    const int blk = blockIdx.x;

    // --- register this block with its physical XCD ---
    if (threadIdx.x == 0) {
        unsigned xcc;
        asm volatile("s_getreg_b32 %0, hwreg(HW_REG_XCC_ID)" : "=s"(xcc));
        xcc &= 7u;
        unsigned slot = __hip_atomic_fetch_add(reg8 + xcc * 64, 1u,
                                               __ATOMIC_RELAXED,
                                               __HIP_MEMORY_SCOPE_AGENT);
        shinfo[0] = xcc; shinfo[1] = slot;
    }
    gridbar(bctrs, bepoch, 1, blk);     // registration settled device-wide
    if (threadIdx.x == 0) {
        unsigned ok = 1;
#pragma unroll
        for (int k = 0; k < 8; ++k)
            ok &= (__hip_atomic_load(reg8 + k * 64, __ATOMIC_RELAXED,
                                     __HIP_MEMORY_SCOPE_AGENT) == 32u);
        shinfo[2] = ok;
    }
    __syncthreads();
    const unsigned grp  = shinfo[0];
    const unsigned slot = shinfo[1];
    const bool grouped  = (shinfo[2] != 0u);

    if (grouped) {
        // XCD k owns batches {2k,2k+1}: global rows [512k, 512k+512).
        const int m0 = (int)grp * 512 + (int)(slot >> 2) * 64;
        const int n0 = (int)(slot & 3) * 96;
        const int gid = (int)slot * 512 + threadIdx.x;
        unsigned* gs = xslots + grp * 32 * 32;    // this XCD's 32 slots
        unsigned bar = 0;
        for (int t = -1; t < 64; ++t) {
            conv_pair(t, m0, n0, threadIdx.x, As, Bs, xpad, h0, h1, h0bn,
                      Wt0, Wt1, b0, b1, gates0, gates1);
            xbar(gs, (int)slot, (++bar) * 32u);
            phaseB_group(t, (int)grp, gid, gates0, gates1, c0, c1, h0, h1,
                         h0bn, hall, g0, be0, mu0, v0, g1, be1, mu1, v1);
            xbar(gs, (int)slot, (++bar) * 32u);
        }
    } else {
        const int m0 = (blk >> 2) * 64;
        const int n0 = (blk & 3) * 96;
        const int gtid = blk * 512 + threadIdx.x;
        unsigned bar = 1;                   // epoch 1 used by registration
        for (int t = -1; t < 64; ++t) {
            conv_pair(t, m0, n0, threadIdx.x, As, Bs, xpad, h0, h1, h0bn,
                      Wt0, Wt1, b0, b1, gates0, gates1);
            gridbar(bctrs, bepoch, ++bar, blk);
            phaseB_body(t, gtid, gates0, gates1, c0, c1, h0, h1, h0bn, hall,
                        g0, be0, mu0, v0, g1, be1, mu1, v1);
            gridbar(bctrs, bepoch, ++bar, blk);
        }
    }
}

// ---------------------------------------------------------------------------
// fallback per-step kernels (used only if cooperative launch itself fails)
// ---------------------------------------------------------------------------
__global__ __launch_bounds__(512, 2) void stepA(int t,
    const u16* xpad, u16* h0, u16* h1, u16* h0bn,
    const u16* Wt0, const u16* Wt1, const float* b0, const float* b1,
    float* gates0, float* gates1)
{
    __shared__ u16 As[2][2][64][40];
    __shared__ u16 Bs[2][2][96][40];
    conv_pair(t, (blockIdx.x >> 2) * 64, (blockIdx.x & 3) * 96, threadIdx.x,
              As, Bs, xpad, h0, h1, h0bn, Wt0, Wt1, b0, b1, gates0, gates1);
}

__global__ __launch_bounds__(256) void stepB(int t,
    const float* gates0, const float* gates1,
    float* c0, float* c1, u16* h0, u16* h1, u16* h0bn, u16* hall,
    const float* g0, const float* be0, const float* mu0, const float* v0,
    const float* g1, const float* be1, const float* mu1, const float* v1)
{
    const int gtid = blockIdx.x * 256 + threadIdx.x;   // 512 blocks -> <131072
    phaseB_body(t, gtid, gates0, gates1, c0, c1, h0, h1, h0bn, hall,
                g0, be0, mu0, v0, g1, be1, mu1, v1);
}

// ---------------------------------------------------------------------------
// dense tail (unchanged)
// ---------------------------------------------------------------------------
__global__ void dense_partial(const u16* __restrict__ hall,
                              const float* __restrict__ Wd,
                              float* __restrict__ partial)
{
    const int k0 = blockIdx.x * 2048;
    const int tt = k0 / 24576;
    const int r0 = k0 - tt * 24576;
    const int t  = threadIdx.x;          // 0..159
    const int b  = t / 10;
    const int nc = t - b * 10;
    const u16* hp = hall + (size_t)(tt * 16 + b) * 24576 + r0;
    const float* wp = Wd + (size_t)k0 * 10 + nc;
    float acc = 0.0f;
    for (int j = 0; j < 2048; j += 8) {
        const u16x8 hv = *(const u16x8*)(hp + j);
#pragma unroll
        for (int u = 0; u < 8; ++u)
            acc = fmaf(bf2f(hv[u]), wp[(size_t)(j + u) * 10], acc);
    }
    partial[blockIdx.x * 160 + t] = acc;
}

__global__ void dense_reduce(const float* __restrict__ partial,
                             const float* __restrict__ bd,
                             float* __restrict__ out)
{
    const int t = threadIdx.x;           // 0..159
    const int nc = t - (t / 10) * 10;
    float acc = bd[nc];
    for (int p = 0; p < 768; ++p) acc += partial[p * 160 + t];
    out[t] = acc;
}

// ---------------------------------------------------------------------------
extern "C" void kernel_launch(void* const* d_in, const int* in_sizes, int n_in,
                              void* d_out, int out_size, void* d_ws, size_t ws_size,
                              hipStream_t stream)
{
    const float* x    = (const float*)d_in[0];
    const float* Wx0  = (const float*)d_in[1];
    const float* Wh0  = (const float*)d_in[2];
    const float* b0p  = (const float*)d_in[3];
    const float* g0p  = (const float*)d_in[4];
    const float* be0p = (const float*)d_in[5];
    const float* mu0p = (const float*)d_in[6];
    const float* v0p  = (const float*)d_in[7];
    const float* Wx1  = (const float*)d_in[8];
    const float* Wh1  = (const float*)d_in[9];
    const float* b1p  = (const float*)d_in[10];
    const float* g1p  = (const float*)d_in[11];
    const float* be1p = (const float*)d_in[12];
    const float* mu1p = (const float*)d_in[13];
    const float* v1p  = (const float*)d_in[14];
    const float* Wd   = (const float*)d_in[15];
    const float* bd   = (const float*)d_in[16];
    float* out = (float*)d_out;

    char* base = (char*)d_ws;
    u16*   h0     = (u16*)(base);                      //   786432 B
    u16*   h1     = (u16*)(base + 786432);             //   786432 B
    float* c0     = (float*)(base + 1572864);          //  1572864 B
    float* c1     = (float*)(base + 3145728);          //  1572864 B
    u16*   h0bn   = (u16*)(base + 4718592);            //   786432 B
    float* gates0 = (float*)(base + 5505024);          //  6291456 B
    float* gates1 = (float*)(base + 11796480);         //  6291456 B
    u16*   xpad   = (u16*)(base + 18087936);           //  4194304 B
    u16*   Wt0    = (u16*)(base + 22282240);           //   737280 B
    u16*   Wt1    = (u16*)(base + 23019520);           //  1327104 B
    u16*   hall   = (u16*)(base + 24346624);           // 50331648 B
    float* part   = (float*)(base + 74678272);         //   491520 B
    unsigned* bctrs  = (unsigned*)(base + 75169792);   //  16384 B (64 x 256B)
    unsigned* bepoch = (unsigned*)(base + 75186176);   //    256 B
    unsigned* reg8   = (unsigned*)(base + 75186432);   //   2048 B (8 x 256B)
    unsigned* xslots = (unsigned*)(base + 75188480);   //  32768 B (8x32x128B)

    hipMemsetAsync(base, 0, 4718592, stream);          // h0,h1,c0,c1,h0bn = 0
    hipMemsetAsync(bctrs, 0, 51456, stream);           // all barrier state = 0

    prep_x <<<1024, 256, 0, stream>>>(x, xpad);
    wtrans0<<<1440, 256, 0, stream>>>(Wx0, Wh0, Wt0);
    wtrans1<<<2592, 256, 0, stream>>>(Wx1, Wh1, Wt1);

    void* args[] = {
        (void*)&bctrs, (void*)&bepoch, (void*)&reg8, (void*)&xslots,
        (void*)&xpad, (void*)&h0, (void*)&h1, (void*)&c0, (void*)&c1,
        (void*)&h0bn, (void*)&gates0, (void*)&gates1, (void*)&hall,
        (void*)&Wt0, (void*)&Wt1, (void*)&b0p, (void*)&b1p,
        (void*)&g0p, (void*)&be0p, (void*)&mu0p, (void*)&v0p,
        (void*)&g1p, (void*)&be1p, (void*)&mu1p, (void*)&v1p
    };
    hipError_t ce = hipLaunchCooperativeKernel((void*)fused, dim3(256),
                                               dim3(512), args, 0, stream);
    if (ce != hipSuccess) {
        (void)hipGetLastError();   // clear sticky error, use fallback path
        for (int t = -1; t < 64; ++t) {
            stepA<<<256, 512, 0, stream>>>(t, xpad, h0, h1, h0bn,
                                           Wt0, Wt1, b0p, b1p, gates0, gates1);
            stepB<<<512, 256, 0, stream>>>(t, gates0, gates1, c0, c1, h0, h1,
                                           h0bn, hall, g0p, be0p, mu0p, v0p,
                                           g1p, be1p, mu1p, v1p);
        }
    }

    dense_partial<<<768, 160, 0, stream>>>(hall, Wd, part);
    dense_reduce <<<1, 160, 0, stream>>>(part, bd, out);
}

// Round 10
// 1974.549 us; speedup vs baseline: 7.2244x; 1.2541x over previous
//
#include <hip/hip_runtime.h>
#include <math.h>

// ImuModel v10: XCD-local persistent ConvLSTM with FUSED pointwise epilogue.
// vs v9: (1) Wt columns permuted so each 96-col n-tile = 4 gates x 24 features
//        -> LSTM pw computed in the conv epilogue (acc staged through the
//        recycled As/Bs LDS, c-state in 6 VGPRs for all 64 steps).
//        (2) ONE phase + ONE barrier per step (65 total, was 130). gates/c
//        global traffic eliminated (~1GB/call). h0/h1/h0bn double-buffered by
//        step parity (conv[t] reads parity p while producers write p^1).
//        (3) dense tail: Wd pre-transposed to bf16 WdT -> contiguous loads.

typedef __attribute__((ext_vector_type(8))) short     bf16x8;
typedef __attribute__((ext_vector_type(8))) unsigned short u16x8;
typedef __attribute__((ext_vector_type(4))) float     f32x4;
typedef unsigned short u16;

#define RS 393216   // h-state elems per step-buffer: 4096*96

__device__ __forceinline__ float hsig(float x) {
    return fminf(fmaxf(0.2f * x + 0.5f, 0.0f), 1.0f);
}
__device__ __forceinline__ float bf2f(u16 u) {
    union { unsigned int i; float f; } v; v.i = ((unsigned int)u) << 16; return v.f;
}
__device__ __forceinline__ u16 f2bf(float f) {
    union { float f; unsigned int i; } v; v.f = f;
    unsigned int r = (v.i + 0x7FFFu + ((v.i >> 16) & 1u)) >> 16;   // RNE
    return (u16)r;
}

// ---------------- global two-level barrier (registration + fallback) --------
__device__ __forceinline__ void gridbar(unsigned* ctrs, unsigned* epoch,
                                        unsigned k, int blk)
{
    __syncthreads();
    if (threadIdx.x == 0) {
        __builtin_amdgcn_fence(__ATOMIC_RELEASE, "agent");
        __hip_atomic_fetch_add(ctrs + (blk & 63) * 64, 1u,
                               __ATOMIC_RELAXED, __HIP_MEMORY_SCOPE_AGENT);
    }
    if (blk == 0 && threadIdx.x < 64) {
        const unsigned target = k * 256u;
        unsigned sum;
        do {
            unsigned v = __hip_atomic_load(ctrs + threadIdx.x * 64,
                                           __ATOMIC_RELAXED,
                                           __HIP_MEMORY_SCOPE_AGENT);
            sum = v;
#pragma unroll
            for (int m = 1; m < 64; m <<= 1)
                sum += __shfl_xor(sum, m, 64);
            if (sum < target) __builtin_amdgcn_s_sleep(2);
        } while (sum < target);
        if (threadIdx.x == 0)
            __hip_atomic_store(epoch, k, __ATOMIC_RELAXED,
                               __HIP_MEMORY_SCOPE_AGENT);
    }
    if (threadIdx.x == 0) {
        while (__hip_atomic_load(epoch, __ATOMIC_RELAXED,
                                 __HIP_MEMORY_SCOPE_AGENT) < k)
            __builtin_amdgcn_s_sleep(4);
        __builtin_amdgcn_fence(__ATOMIC_ACQUIRE, "agent");
    }
    __syncthreads();
}

// ---------------- XCD-local barrier (v9, proven) -----------------------------
__device__ __forceinline__ void xbar(unsigned* slots, int myslot,
                                     unsigned target)
{
    __syncthreads();                  // all block stores are in L2 after this
    if (threadIdx.x == 0)
        __hip_atomic_fetch_add(slots + myslot * 32, 1u,
                               __ATOMIC_RELAXED, __HIP_MEMORY_SCOPE_AGENT);
    if (threadIdx.x < 32) {
        unsigned sum;
        do {
            unsigned v = __hip_atomic_load(slots + threadIdx.x * 32,
                                           __ATOMIC_RELAXED,
                                           __HIP_MEMORY_SCOPE_AGENT);
            sum = v;
#pragma unroll
            for (int m = 1; m < 32; m <<= 1)
                sum += __shfl_xor(sum, m, 64);
            if (sum < target) __builtin_amdgcn_s_sleep(2);
        } while (sum < target);
        asm volatile("buffer_inv sc0\n\ts_waitcnt vmcnt(0)" ::: "memory");
    }
    __syncthreads();
}

// ---------------------------------------------------------------------------
// prep kernels. Gate-permutation for Wt rows: out row n (0..383):
//   nt=n/96, j=n%96, g=j/24, fl=j%24  ->  orig col no = g*96 + nt*24 + fl
// ---------------------------------------------------------------------------
__global__ __launch_bounds__(256) void prep_x(const float* __restrict__ x,
                                              u16* __restrict__ xpad)
{
    const int idx = blockIdx.x * 256 + threadIdx.x;      // < 262144
    const int t = idx >> 12, b = (idx >> 8) & 15, p = idx & 255;
    const float* src = x + (((size_t)b * 64 + t) * 256 + p) * 6;
    u16x8 v = {};
    v[0] = f2bf(src[0]); v[1] = f2bf(src[1]); v[2] = f2bf(src[2]);
    v[3] = f2bf(src[3]); v[4] = f2bf(src[4]); v[5] = f2bf(src[5]);
    *(u16x8*)(xpad + (size_t)idx * 8) = v;
}

__global__ __launch_bounds__(256) void wtrans0(const float* __restrict__ Wx0,
                                               const float* __restrict__ Wh0,
                                               u16* __restrict__ Wt0)
{
    const int idx = blockIdx.x * 256 + threadIdx.x;      // < 384*960
    const int n = idx / 960, k = idx - n * 960;
    const int nt = n / 96, j = n - nt * 96;
    const int no = (j / 24) * 96 + nt * 24 + (j % 24);   // permuted gate col
    float v = 0.0f;
    if (k < 96) {
        const int q = k >> 3, c = k & 7;
        if (q < 9 && c < 6) v = Wx0[(q * 6 + c) * 384 + no];
    } else {
        v = Wh0[(k - 96) * 384 + no];
    }
    Wt0[idx] = f2bf(v);
}

__global__ __launch_bounds__(256) void wtrans1(const float* __restrict__ Wx1,
                                               const float* __restrict__ Wh1,
                                               u16* __restrict__ Wt1)
{
    const int idx = blockIdx.x * 256 + threadIdx.x;      // < 384*1728
    const int n = idx / 1728, k = idx - n * 1728;
    const int nt = n / 96, j = n - nt * 96;
    const int no = (j / 24) * 96 + nt * 24 + (j % 24);   // permuted gate col
    const float v = (k < 864) ? Wx1[k * 384 + no] : Wh1[(k - 864) * 384 + no];
    Wt1[idx] = f2bf(v);
}

// Wd [1572864][10] f32 -> WdT [10][1572864] bf16
__global__ __launch_bounds__(256) void wtransD(const float* __restrict__ Wd,
                                               u16* __restrict__ WdT)
{
    const int k = blockIdx.x * 256 + threadIdx.x;        // < 1572864
    const float* src = Wd + (size_t)k * 10;
#pragma unroll
    for (int nc = 0; nc < 10; ++nc)
        WdT[(size_t)nc * 1572864 + k] = f2bf(src[nc]);
}

// ---------------------------------------------------------------------------
// one fused phase: half0 = conv1[t]+pw1[t], half1 = conv0[t+1]+pw0[t+1].
// lds: 51200B; per half 25600B = union{ As[2][64][40]+Bs[2][96][40] u16,
//                                       accS[64][100] f32 }.
// c-state: cregs[6] per thread, owned by (tile, htid, q) -- persistent.
// ---------------------------------------------------------------------------
__device__ void phase(int t, int m0, int n0, int tidx, char* lds,
    const u16* __restrict__ xpad, u16* __restrict__ h0b,
    u16* __restrict__ h1b, u16* __restrict__ h0bnb, u16* __restrict__ hall,
    const u16* __restrict__ Wt0, const u16* __restrict__ Wt1,
    const float* __restrict__ b0, const float* __restrict__ b1,
    const float* __restrict__ g0, const float* __restrict__ be0,
    const float* __restrict__ mu0, const float* __restrict__ v0,
    const float* __restrict__ g1, const float* __restrict__ be1,
    const float* __restrict__ mu1, const float* __restrict__ v1,
    float (&cregs)[6])
{
    const int half = tidx >> 8;           // 0: conv1[t], 1: conv0[t+1]
    const int htid = tidx & 255;
    const bool active = half ? (t < 63) : (t >= 0);

    // step-parity buffers (see header): conv1[t] reads h1[t-1],h0bn[t];
    // conv0[t+1] reads h0[t],xpad[t+1]; writers use opposite parity.
    const u16* in0 = half ? (xpad + (size_t)(t + 1) * 32768)
                          : (h0bnb + (size_t)(t & 1) * RS);
    const u16* in1 = half ? (h0b + (size_t)(t & 1) * RS)
                          : (h1b + (size_t)((t - 1) & 1) * RS);
    u16* hraw_out = half ? (h0b + (size_t)((t + 1) & 1) * RS)
                         : (h1b + (size_t)(t & 1) * RS);
    u16* hbn_out  = half ? (h0bnb + (size_t)((t + 1) & 1) * RS)
                         : (hall + (size_t)(t < 0 ? 0 : t) * RS);

    const int lane = htid & 63;
    const int hw   = htid >> 6;
    const int wm = hw >> 1, wn = hw & 1;
    const int fr = lane & 15, fg = lane >> 4;
    const int arow = htid >> 2, seg = htid & 3;
    const int mg = m0 + arow;
    const int py = (mg >> 4) & 15, px = mg & 15, pb = mg >> 8;
    const int nt = n0 / 96;

    const int   KT   = half ? 960 : 1728;
    const int   NS0  = half ? 3   : 27;
    const int   MYST = half ? 30  : 54;
    const u16*  Wt   = half ? Wt0 : Wt1;

    u16*   AsB  = (u16*)(lds + half * 25600);        // [buf][64][40]
    u16*   BsB  = AsB + 5120;                        // [buf][96][40]
    float* accS = (float*)(lds + half * 25600);      // [64][100]

    f32x4 acc[2][3];
#pragma unroll
    for (int i = 0; i < 2; ++i)
#pragma unroll
        for (int j = 0; j < 3; ++j) acc[i][j] = (f32x4){0.f, 0.f, 0.f, 0.f};

    u16x8 va, vb0, vb1;
    auto stage = [&](int ks) {
        u16x8 z = {};
        va = z;
        if (half && ks < 3) {
            const int q = ks * 4 + seg;           // 12 taps, q<9 real
            const int qd = q / 3;
            const int yy = py + qd - 1;
            const int xx = px + (q - 3 * qd) - 1;
            if (q < 9 && (unsigned)yy < 16u && (unsigned)xx < 16u)
                va = *(const u16x8*)(in0 + (size_t)((pb << 8) + yy * 16 + xx) * 8);
        } else {
            const int s = (ks < NS0) ? ks : ks - NS0;
            const u16* src = (ks < NS0) ? in0 : in1;
            const int q = s / 3;
            const int c0v = (s - 3 * q) * 32 + seg * 8;
            const int qd = q / 3;
            const int yy = py + qd - 1;
            const int xx = px + (q - 3 * qd) - 1;
            if ((unsigned)yy < 16u && (unsigned)xx < 16u)
                va = *(const u16x8*)(src + (size_t)((pb << 8) + yy * 16 + xx) * 96 + c0v);
        }
        const int koff = ks * 32 + seg * 8;
        vb0 = *(const u16x8*)(Wt + (size_t)(n0 + arow) * KT + koff);
        vb1 = z;
        if (htid < 128)
            vb1 = *(const u16x8*)(Wt + (size_t)(n0 + 64 + arow) * KT + koff);
    };
    auto ldsw = [&](int buf) {
        *(u16x8*)(AsB + buf * 2560 + arow * 40 + seg * 8) = va;
        *(u16x8*)(BsB + buf * 3840 + arow * 40 + seg * 8) = vb0;
        if (htid < 128)
            *(u16x8*)(BsB + buf * 3840 + (64 + arow) * 40 + seg * 8) = vb1;
    };

    if (active) { stage(0); ldsw(0); }
    __syncthreads();

    for (int ks = 0; ks < 54; ++ks) {
        const int cur = ks & 1;
        if (active && ks < MYST) {
            if (ks + 1 < MYST) stage(ks + 1);

            bf16x8 af[2], bq[3];
#pragma unroll
            for (int mf = 0; mf < 2; ++mf)
                af[mf] = *(const bf16x8*)(AsB + cur * 2560 +
                                          (wm * 32 + mf * 16 + fr) * 40 + fg * 8);
#pragma unroll
            for (int nf = 0; nf < 3; ++nf)
                bq[nf] = *(const bf16x8*)(BsB + cur * 3840 +
                                          (wn * 48 + nf * 16 + fr) * 40 + fg * 8);

            __builtin_amdgcn_s_setprio(1);
#pragma unroll
            for (int mf = 0; mf < 2; ++mf)
#pragma unroll
                for (int nf = 0; nf < 3; ++nf)
                    acc[mf][nf] = __builtin_amdgcn_mfma_f32_16x16x32_bf16(
                        af[mf], bq[nf], acc[mf][nf], 0, 0, 0);
            __builtin_amdgcn_s_setprio(0);

            if (ks + 1 < MYST) ldsw(cur ^ 1);
        }
        __syncthreads();   // common site for both halves
    }
    // k-loop done; As/Bs dead -> recycle as accS.

    // E1: acc + bias -> accS[row][col]
    if (active) {
        const float* bias = half ? b0 : b1;
#pragma unroll
        for (int nf = 0; nf < 3; ++nf) {
            const int col = wn * 48 + nf * 16 + fr;
            const float bi = bias[(col / 24) * 96 + nt * 24 + (col % 24)];
#pragma unroll
            for (int mf = 0; mf < 2; ++mf) {
                const int row = wm * 32 + mf * 16 + fg * 4;
#pragma unroll
                for (int r = 0; r < 4; ++r)
                    accS[(row + r) * 100 + col] = acc[mf][nf][r] + bi;
            }
        }
    }
    __syncthreads();

    // E2: LSTM pointwise + BN, c in registers, h/hbn to global (parity bufs)
    if (active) {
        const float* gam = half ? g0 : g1;
        const float* bet = half ? be0 : be1;
        const float* muv = half ? mu0 : mu1;
        const float* var = half ? v0  : v1;
#pragma unroll
        for (int q = 0; q < 6; ++q) {
            const int item = htid + 256 * q;          // < 1536
            const int r = item / 24, fl = item - r * 24;
            const float gi = accS[r * 100 + fl];
            const float gf = accS[r * 100 + 24 + fl];
            const float gc = accS[r * 100 + 48 + fl];
            const float go = accS[r * 100 + 72 + fl];
            const int f = nt * 24 + fl;
            const float i_ = hsig(gi);
            const float f_ = hsig(gf);
            const float o_ = hsig(go);
            const float c_ = f_ * cregs[q] + i_ * tanhf(gc);
            const float h_ = o_ * tanhf(c_);
            cregs[q] = c_;
            hraw_out[(size_t)(m0 + r) * 96 + f] = f2bf(h_);
            const float s = gam[f] * rsqrtf(var[f] + 1e-3f);
            hbn_out[(size_t)(m0 + r) * 96 + f] =
                f2bf((h_ - muv[f]) * s + bet[f]);
        }
    }
    // caller's barrier (__syncthreads inside) orders accS reads vs next phase
}

// ---------------------------------------------------------------------------
// persistent kernel: XCD-grouped if placement allows, else global barriers
// ---------------------------------------------------------------------------
__global__ __launch_bounds__(512, 2) void fused(
    unsigned* bctrs, unsigned* bepoch, unsigned* reg8, unsigned* xslots,
    const u16* xpad, u16* h0b, u16* h1b, u16* h0bnb, u16* hall,
    const u16* Wt0, const u16* Wt1,
    const float* b0, const float* b1,
    const float* g0, const float* be0, const float* mu0, const float* v0,
    const float* g1, const float* be1, const float* mu1, const float* v1)
{
    __shared__ char lds[51200];
    __shared__ unsigned shinfo[3];      // xcc, slot, ok
    const int blk = blockIdx.x;

    if (threadIdx.x == 0) {
        unsigned xcc;
        asm volatile("s_getreg_b32 %0, hwreg(HW_REG_XCC_ID)" : "=s"(xcc));
        xcc &= 7u;
        unsigned slot = __hip_atomic_fetch_add(reg8 + xcc * 64, 1u,
                                               __ATOMIC_RELAXED,
                                               __HIP_MEMORY_SCOPE_AGENT);
        shinfo[0] = xcc; shinfo[1] = slot;
    }
    gridbar(bctrs, bepoch, 1, blk);     // registration settled device-wide
    if (threadIdx.x == 0) {
        unsigned ok = 1;
#pragma unroll
        for (int k = 0; k < 8; ++k)
            ok &= (__hip_atomic_load(reg8 + k * 64, __ATOMIC_RELAXED,
                                     __HIP_MEMORY_SCOPE_AGENT) == 32u);
        shinfo[2] = ok;
    }
    __syncthreads();
    const unsigned grp  = shinfo[0];
    const unsigned slot = shinfo[1];
    const bool grouped  = (shinfo[2] != 0u);

    float cregs[6] = {0.f, 0.f, 0.f, 0.f, 0.f, 0.f};

    if (grouped) {
        const int m0 = (int)grp * 512 + (int)(slot >> 2) * 64;
        const int n0 = (int)(slot & 3) * 96;
        unsigned* gs = xslots + grp * 1024;
        unsigned bar = 0;
        for (int t = -1; t < 64; ++t) {
            phase(t, m0, n0, threadIdx.x, lds, xpad, h0b, h1b, h0bnb, hall,
                  Wt0, Wt1, b0, b1, g0, be0, mu0, v0, g1, be1, mu1, v1, cregs);
            xbar(gs, (int)slot, (++bar) * 32u);
        }
    } else {
        const int m0 = (blk >> 2) * 64;
        const int n0 = (blk & 3) * 96;
        unsigned bar = 1;                   // epoch 1 used by registration
        for (int t = -1; t < 64; ++t) {
            phase(t, m0, n0, threadIdx.x, lds, xpad, h0b, h1b, h0bnb, hall,
                  Wt0, Wt1, b0, b1, g0, be0, mu0, v0, g1, be1, mu1, v1, cregs);
            gridbar(bctrs, bepoch, ++bar, blk);
        }
    }
}

// ---------------------------------------------------------------------------
// launch-fallback per-step kernel (c-state round-trips through global)
// ---------------------------------------------------------------------------
__global__ __launch_bounds__(512, 2) void stepF(int t,
    const u16* xpad, u16* h0b, u16* h1b, u16* h0bnb, u16* hall,
    const u16* Wt0, const u16* Wt1,
    const float* b0, const float* b1,
    const float* g0, const float* be0, const float* mu0, const float* v0,
    const float* g1, const float* be1, const float* mu1, const float* v1,
    float* c0g, float* c1g)
{
    __shared__ char lds[51200];
    const int m0 = (blockIdx.x >> 2) * 64;
    const int n0 = (blockIdx.x & 3) * 96;
    const int half = threadIdx.x >> 8;
    const int htid = threadIdx.x & 255;
    const int nt = n0 / 96;
    float* cst = half ? c0g : c1g;

    float cregs[6];
#pragma unroll
    for (int q = 0; q < 6; ++q) {
        const int item = htid + 256 * q;
        const int r = item / 24, fl = item - r * 24;
        cregs[q] = cst[(size_t)(m0 + r) * 96 + nt * 24 + fl];
    }
    phase(t, m0, n0, threadIdx.x, lds, xpad, h0b, h1b, h0bnb, hall,
          Wt0, Wt1, b0, b1, g0, be0, mu0, v0, g1, be1, mu1, v1, cregs);
#pragma unroll
    for (int q = 0; q < 6; ++q) {
        const int item = htid + 256 * q;
        const int r = item / 24, fl = item - r * 24;
        cst[(size_t)(m0 + r) * 96 + nt * 24 + fl] = cregs[q];
    }
}

// ---------------------------------------------------------------------------
// dense tail: bf16 x bf16, both operands contiguous
// ---------------------------------------------------------------------------
__global__ void dense_partial(const u16* __restrict__ hall,
                              const u16* __restrict__ WdT,
                              float* __restrict__ partial)
{
    const int k0 = blockIdx.x * 2048;
    const int tt = k0 / 24576;
    const int r0 = k0 - tt * 24576;
    const int th = threadIdx.x;          // 0..159
    const int b  = th / 10;
    const int nc = th - b * 10;
    const u16* hp = hall + (size_t)(tt * 16 + b) * 24576 + r0;
    const u16* wp = WdT + (size_t)nc * 1572864 + k0;
    float acc = 0.0f;
    for (int j = 0; j < 2048; j += 8) {
        const u16x8 hv = *(const u16x8*)(hp + j);
        const u16x8 wv = *(const u16x8*)(wp + j);
#pragma unroll
        for (int u = 0; u < 8; ++u)
            acc = fmaf(bf2f(hv[u]), bf2f(wv[u]), acc);
    }
    partial[blockIdx.x * 160 + th] = acc;
}

__global__ void dense_reduce(const float* __restrict__ partial,
                             const float* __restrict__ bd,
                             float* __restrict__ out)
{
    const int t = threadIdx.x;           // 0..159
    const int nc = t - (t / 10) * 10;
    float acc = bd[nc];
    for (int p = 0; p < 768; ++p) acc += partial[p * 160 + t];
    out[t] = acc;
}

// ---------------------------------------------------------------------------
extern "C" void kernel_launch(void* const* d_in, const int* in_sizes, int n_in,
                              void* d_out, int out_size, void* d_ws, size_t ws_size,
                              hipStream_t stream)
{
    const float* x    = (const float*)d_in[0];
    const float* Wx0  = (const float*)d_in[1];
    const float* Wh0  = (const float*)d_in[2];
    const float* b0p  = (const float*)d_in[3];
    const float* g0p  = (const float*)d_in[4];
    const float* be0p = (const float*)d_in[5];
    const float* mu0p = (const float*)d_in[6];
    const float* v0p  = (const float*)d_in[7];
    const float* Wx1  = (const float*)d_in[8];
    const float* Wh1  = (const float*)d_in[9];
    const float* b1p  = (const float*)d_in[10];
    const float* g1p  = (const float*)d_in[11];
    const float* be1p = (const float*)d_in[12];
    const float* mu1p = (const float*)d_in[13];
    const float* v1p  = (const float*)d_in[14];
    const float* Wd   = (const float*)d_in[15];
    const float* bd   = (const float*)d_in[16];
    float* out = (float*)d_out;

    char* base = (char*)d_ws;
    u16*   h0b    = (u16*)(base);                      //  1572864 B (2 par)
    u16*   h1b    = (u16*)(base + 1572864);            //  1572864 B
    u16*   h0bnb  = (u16*)(base + 3145728);            //  1572864 B
    float* c0g    = (float*)(base + 4718592);          //  1572864 B (fallback)
    float* c1g    = (float*)(base + 6291456);          //  1572864 B
    u16*   xpad   = (u16*)(base + 7864320);            //  4194304 B
    u16*   Wt0    = (u16*)(base + 12058624);           //   737280 B
    u16*   Wt1    = (u16*)(base + 12795904);           //  1327104 B
    u16*   hall   = (u16*)(base + 14123008);           // 50331648 B
    float* part   = (float*)(base + 64454656);         //   491520 B
    u16*   WdT    = (u16*)(base + 64946176);           // 31457280 B
    unsigned* bctrs  = (unsigned*)(base + 96403456);   //    16384 B
    unsigned* bepoch = (unsigned*)(base + 96419840);   //      256 B
    unsigned* reg8   = (unsigned*)(base + 96420096);   //     2048 B
    unsigned* xslots = (unsigned*)(base + 96422144);   //    32768 B

    hipMemsetAsync(base, 0, 7864320, stream);          // h/hbn/c states = 0
    hipMemsetAsync(bctrs, 0, 51456, stream);           // all barrier state

    prep_x <<<1024, 256, 0, stream>>>(x, xpad);
    wtrans0<<<1440, 256, 0, stream>>>(Wx0, Wh0, Wt0);
    wtrans1<<<2592, 256, 0, stream>>>(Wx1, Wh1, Wt1);
    wtransD<<<6144, 256, 0, stream>>>(Wd, WdT);

    void* args[] = {
        (void*)&bctrs, (void*)&bepoch, (void*)&reg8, (void*)&xslots,
        (void*)&xpad, (void*)&h0b, (void*)&h1b, (void*)&h0bnb, (void*)&hall,
        (void*)&Wt0, (void*)&Wt1, (void*)&b0p, (void*)&b1p,
        (void*)&g0p, (void*)&be0p, (void*)&mu0p, (void*)&v0p,
        (void*)&g1p, (void*)&be1p, (void*)&mu1p, (void*)&v1p
    };
    hipError_t ce = hipLaunchCooperativeKernel((void*)fused, dim3(256),
                                               dim3(512), args, 0, stream);
    if (ce != hipSuccess) {
        (void)hipGetLastError();   // clear sticky error, use fallback path
        for (int t = -1; t < 64; ++t) {
            stepF<<<256, 512, 0, stream>>>(t, xpad, h0b, h1b, h0bnb, hall,
                                           Wt0, Wt1, b0p, b1p,
                                           g0p, be0p, mu0p, v0p,
                                           g1p, be1p, mu1p, v1p, c0g, c1g);
        }
    }

    dense_partial<<<768, 160, 0, stream>>>(hall, WdT, part);
    dense_reduce <<<1, 160, 0, stream>>>(part, bd, out);
}